// Round 1
// baseline (759.178 us; speedup 1.0000x reference)
//
#include <hip/hip_runtime.h>
#include <hip/hip_bf16.h>
#include <hip/hip_fp8.h>
#include <cstdint>
#include <cstddef>

// Problem constants
#define NN     20000     // nodes
#define NF     128       // in features
#define NH     56        // heads
#define OC     32        // out channels per head
#define DD1    1792      // NH*OC
#define NE     100000    // edges (before self loops)
#define ETOT   120000    // edges + self loops
#define NG     50        // graphs
#define EPS_BN 1e-5f
#define GRP    16        // nodes per wave in aggregate
#define EB     16        // edge batch (aggregate loads in flight)

typedef __bf16 bf16x8 __attribute__((ext_vector_type(8)));
typedef float  floatx4 __attribute__((ext_vector_type(4)));
typedef float  floatx2 __attribute__((ext_vector_type(2)));
typedef unsigned int u32;
typedef __attribute__((address_space(1))) u32 gu32;
typedef __attribute__((address_space(3))) u32 lu32;

__device__ __forceinline__ void async_copy16(void* lds, const void* g) {
    __builtin_amdgcn_global_load_lds((gu32*)const_cast<void*>(g), (lu32*)lds, 16, 0, 0);
}

// decode 4 fp8 (e4m3, packed in u32) to 4 floats (HW cvt when available)
__device__ __forceinline__ void dec_fp8x4(u32 u, float* v) {
#if __has_builtin(__builtin_amdgcn_cvt_pk_f32_fp8)
    floatx2 lo = __builtin_amdgcn_cvt_pk_f32_fp8(u, false);
    floatx2 hi = __builtin_amdgcn_cvt_pk_f32_fp8(u, true);
    v[0] = lo[0]; v[1] = lo[1]; v[2] = hi[0]; v[3] = hi[1];
#else
    #pragma unroll
    for (int b = 0; b < 4; ++b) {
        __hip_fp8_e4m3 t;
        t.__x = (u >> (8 * b)) & 0xff;
        v[b] = (float)t;
    }
#endif
}

__device__ __forceinline__ void fma_fp8x4(u32 u, float a, float* acc) {
    float v[4];
    dec_fp8x4(u, v);
    #pragma unroll
    for (int b = 0; b < 4; ++b) acc[b] += a * v[b];
}

// ---------------- elementwise cast fp32 -> bf16 ----------------
__global__ __launch_bounds__(256) void cast_bf16_kernel(const float* __restrict__ in,
                                                        __hip_bfloat16* __restrict__ out, int n) {
    int i = blockIdx.x * 256 + threadIdx.x;
    if (i < n) out[i] = __float2bfloat16(in[i]);
}

// ---------------- tiled transpose + cast: in[R][C] f32 -> out[C][R] bf16 ----------------
__global__ __launch_bounds__(256) void transpose_cast_kernel(const float* __restrict__ in,
                                                             __hip_bfloat16* __restrict__ out,
                                                             int R, int C) {
    __shared__ float tile[32][33];
    int c0 = blockIdx.x * 32, r0 = blockIdx.y * 32;
    int tx = threadIdx.x & 31, ty = threadIdx.x >> 5;   // ty in 0..7
    #pragma unroll
    for (int i = 0; i < 32; i += 8) {
        int r = r0 + ty + i, c = c0 + tx;
        if (r < R && c < C) tile[ty + i][tx] = in[(size_t)r * C + c];
    }
    __syncthreads();
    #pragma unroll
    for (int i = 0; i < 32; i += 8) {
        int c = c0 + ty + i, r = r0 + tx;
        if (c < C && r < R) out[(size_t)c * R + r] = __float2bfloat16(tile[tx][ty + i]);
    }
}

// ---------------- CSR build: histogram / scan / scatter ----------------
__global__ __launch_bounds__(256) void hist_kernel(const int* __restrict__ ei, int* __restrict__ deg) {
    int i = blockIdx.x * 256 + threadIdx.x;
    if (i >= ETOT) return;
    int dst = (i < NE) ? ei[NE + i] : (i - NE);
    atomicAdd(&deg[dst], 1);
}

__global__ __launch_bounds__(1024) void scan_kernel(const int* __restrict__ deg,
                                                    int* __restrict__ rowptr,
                                                    int* __restrict__ cursor) {
    __shared__ int buf[1024];
    int t = threadIdx.x;
    const int CH = (NN + 1023) >> 10;   // 20
    int base = t * CH;
    int s = 0;
    for (int j = 0; j < CH; ++j) { int idx = base + j; if (idx < NN) s += deg[idx]; }
    buf[t] = s;
    __syncthreads();
    for (int off = 1; off < 1024; off <<= 1) {
        int v = (t >= off) ? buf[t - off] : 0;
        __syncthreads();
        buf[t] += v;
        __syncthreads();
    }
    int run = buf[t] - s;   // exclusive
    for (int j = 0; j < CH; ++j) {
        int idx = base + j;
        if (idx < NN) { rowptr[idx] = run; cursor[idx] = run; run += deg[idx]; }
    }
    if (t == 1023) rowptr[NN] = buf[1023];
}

__global__ __launch_bounds__(256) void scatter_kernel(const int* __restrict__ ei,
                                                      int* __restrict__ cursor,
                                                      int* __restrict__ csr_src) {
    int i = blockIdx.x * 256 + threadIdx.x;
    if (i >= ETOT) return;
    int s, d;
    if (i < NE) { s = ei[i]; d = ei[NE + i]; } else { s = i - NE; d = i - NE; }
    int pos = atomicAdd(&cursor[d], 1);
    csr_src[pos] = s;
}

// ---------------- bf16 MFMA GEMM, 256x256 tile, deep-pipelined ----------------
// 8 waves (2M x 4N), BK=32, 4-deep LDS ring (4 x 32 KiB), prefetch distance 3.
// Counted s_waitcnt vmcnt(12) — the global_load_lds queue is NEVER drained in the
// main loop (T4); raw s_barrier (no implicit vmcnt(0) drain); s_setprio around the
// two 16-MFMA phases (T5). Bank-conflict-free LDS reads via pre-swizzled global
// source seg ^ ((row>>1)&3) with linear global_load_lds dest (rule #21).
// Race-freedom: tile t's 4 loads/wave are complete at vmcnt(12) and globally
// visible after the following barrier; the buffer overwritten by stage(t+3)
// (= buf[(t-1)&3]) had all reads consumed (lgkmcnt before MFMA) before the
// end-barrier of iteration t-1, which precedes this stage in program order.
// Tail: re-stage the last K-tile into dead buffers so vmcnt stays uniform.
__global__ __launch_bounds__(512, 2) void gemm_256(const __hip_bfloat16* __restrict__ A,
                                                   const __hip_bfloat16* __restrict__ Bt,
                                                   unsigned char* __restrict__ C8,
                                                   int M, int N, int K) {
    __shared__ __align__(16) unsigned short lds[4][16384];   // [buf][A: 0..8191 | B: 8192..16383]
    const int tid  = threadIdx.x;
    const int lane = tid & 63, wave = tid >> 6;
    const int wm = wave >> 2, wn = wave & 3;     // 2 x 4 wave grid; per-wave C: 128 x 64

    const int nbx = N >> 8;                      // 7
    const int nby = (M + 255) >> 8;              // 79
    const int nwg = nbx * nby;                   // 553
    // bijective XCD swizzle (m204): contiguous wg chunk per XCD; bx fastest => A-panel L2 locality
    const int q = nwg >> 3, r = nwg & 7;
    const int xcd = blockIdx.x & 7, bidx = blockIdx.x >> 3;
    const int wg = (xcd < r ? xcd * (q + 1) : r * (q + 1) + (xcd - r) * q) + bidx;
    const int by = wg / nbx, bx = wg - by * nbx;
    const int m0 = by << 8, n0 = bx << 8;

    const int NT = K >> 5;                       // 56 (layer 2) or 4 (layer 1)

    auto stage = [&](int kt, int b) {
        const int k0 = kt << 5;
        #pragma unroll
        for (int i = 0; i < 2; ++i) {            // A half: 256 rows x 32 cols
            int slot = tid + i * 512;            // 0..1023, 16B each
            int row = slot >> 2, seg = slot & 3;
            int gseg = seg ^ ((row >> 1) & 3);
            int gr = m0 + row; if (gr > M - 1) gr = M - 1;
            async_copy16(&lds[b][slot * 8], A + (size_t)gr * K + k0 + gseg * 8);
        }
        #pragma unroll
        for (int i = 0; i < 2; ++i) {            // B half: 256 rows x 32 cols
            int slot = tid + i * 512;
            int row = slot >> 2, seg = slot & 3;
            int gseg = seg ^ ((row >> 1) & 3);
            async_copy16(&lds[b][8192 + slot * 8], Bt + (size_t)(n0 + row) * K + k0 + gseg * 8);
        }
    };

    floatx4 zero = {0.f, 0.f, 0.f, 0.f};
    floatx4 acc[8][4];
    #pragma unroll
    for (int i = 0; i < 8; ++i)
        #pragma unroll
        for (int jj = 0; jj < 4; ++jj) acc[i][jj] = zero;

    // prologue: 3 tiles in flight (12 loads/wave), no wait
    stage(0, 0);
    stage(1, 1);
    stage(2, 2);

    const int qq = lane >> 4, rr = lane & 15;

    for (int t = 0; t < NT; ++t) {
        int pf = t + 3; if (pf > NT - 1) pf = NT - 1;        // tail: dead-buffer re-stage keeps vmcnt uniform
        stage(pf, (t + 3) & 3);
        asm volatile("s_waitcnt vmcnt(12)" ::: "memory");    // tile t landed; 3 tiles stay in flight
        __builtin_amdgcn_s_barrier();                        // raw barrier: NO vmcnt(0) drain
        __builtin_amdgcn_sched_barrier(0);

        const unsigned short* bufA = &lds[t & 3][0];
        const unsigned short* bufB = &lds[t & 3][8192];

        bf16x8 bF[4], aF[4];
        #pragma unroll
        for (int nt = 0; nt < 4; ++nt) {
            int row = wn * 64 + nt * 16 + rr;
            int seg = qq ^ ((row >> 1) & 3);
            bF[nt] = *(const bf16x8*)&bufB[row * 32 + seg * 8];
        }
        #pragma unroll
        for (int mt = 0; mt < 4; ++mt) {
            int row = wm * 128 + mt * 16 + rr;
            int seg = qq ^ ((row >> 1) & 3);
            aF[mt] = *(const bf16x8*)&bufA[row * 32 + seg * 8];
        }
        __builtin_amdgcn_s_setprio(1);
        #pragma unroll
        for (int mt = 0; mt < 4; ++mt)
            #pragma unroll
            for (int nt = 0; nt < 4; ++nt)
                acc[mt][nt] = __builtin_amdgcn_mfma_f32_16x16x32_bf16(aF[mt], bF[nt], acc[mt][nt], 0, 0, 0);
        __builtin_amdgcn_s_setprio(0);
        #pragma unroll
        for (int mt = 0; mt < 4; ++mt) {
            int row = wm * 128 + 64 + mt * 16 + rr;
            int seg = qq ^ ((row >> 1) & 3);
            aF[mt] = *(const bf16x8*)&bufA[row * 32 + seg * 8];
        }
        __builtin_amdgcn_s_setprio(1);
        #pragma unroll
        for (int mt = 0; mt < 4; ++mt)
            #pragma unroll
            for (int nt = 0; nt < 4; ++nt)
                acc[4 + mt][nt] = __builtin_amdgcn_mfma_f32_16x16x32_bf16(aF[mt], bF[nt], acc[4 + mt][nt], 0, 0, 0);
        __builtin_amdgcn_s_setprio(0);

        __builtin_amdgcn_sched_barrier(0);
        asm volatile("" ::: "memory");
        __builtin_amdgcn_s_barrier();                        // reads of buf[t&3] done before next stage overwrites it
    }

    // epilogue: fp8 quantize + store
    #pragma unroll
    for (int mt = 0; mt < 8; ++mt) {
        #pragma unroll
        for (int r4 = 0; r4 < 4; ++r4) {
            int rowc = m0 + wm * 128 + mt * 16 + (lane >> 4) * 4 + r4;
            if (rowc < M) {
                float v0 = acc[mt][0][r4], v1 = acc[mt][1][r4];
                float v2 = acc[mt][2][r4], v3 = acc[mt][3][r4];
                unsigned char q8[4];
#if __has_builtin(__builtin_amdgcn_cvt_pk_fp8_f32)
                u32 p01 = (u32)__builtin_amdgcn_cvt_pk_fp8_f32(v0, v1, 0, false);
                u32 p23 = (u32)__builtin_amdgcn_cvt_pk_fp8_f32(v2, v3, 0, false);
                q8[0] = p01 & 0xff; q8[1] = (p01 >> 8) & 0xff;
                q8[2] = p23 & 0xff; q8[3] = (p23 >> 8) & 0xff;
#else
                { __hip_fp8_e4m3 t0(v0), t1(v1), t2(v2), t3(v3);
                  q8[0] = t0.__x; q8[1] = t1.__x; q8[2] = t2.__x; q8[3] = t3.__x; }
#endif
                #pragma unroll
                for (int nt = 0; nt < 4; ++nt) {
                    int col = n0 + wn * 64 + nt * 16 + (lane & 15);
                    C8[(size_t)rowc * N + col] = q8[nt];
                }
            }
        }
    }
}

// ---------------- attention scores from fp8 h: as/ad[n,h] = sum_o h[n,h,o]*att[h,o] ----------------
__global__ __launch_bounds__(256) void attn_score(const unsigned char* __restrict__ h8,
                                                  const float* __restrict__ att_src,
                                                  const float* __restrict__ att_dst,
                                                  float* __restrict__ as_,
                                                  float* __restrict__ ad_) {
    int wave = threadIdx.x >> 6, lane = threadIdx.x & 63;
    int node = blockIdx.x * 4 + wave;
    if (node >= NN || lane >= NH) return;
    const uint2* hp = (const uint2*)(h8 + (size_t)node * DD1 + lane * OC);   // 32 B / head
    float s = 0.f, d = 0.f;
    #pragma unroll
    for (int jj = 0; jj < 4; ++jj) {
        uint2 u2 = hp[jj];
        u32 us[2] = {u2.x, u2.y};
        #pragma unroll
        for (int w = 0; w < 2; ++w) {
            float v[4];
            dec_fp8x4(us[w], v);
            #pragma unroll
            for (int b = 0; b < 4; ++b) {
                int o = jj * 8 + w * 4 + b;
                s += v[b] * att_src[lane * OC + o];
                d += v[b] * att_dst[lane * OC + o];
            }
        }
    }
    as_[(size_t)node * NH + lane] = s;
    ad_[(size_t)node * NH + lane] = d;
}

// ---------------- node-boundary flush for the fused streaming aggregate ----------------
// acc holds UNNORMALIZED weighted sums; divide by den here.
// LAYER==1: bf16 h1p[cur][slice] = BN1(ELU(acc/den + b1))
// LAYER==2: head-reduce in-wave, write per-slice partial (non-atomic) to h2part[cur][f][32]
template <int LAYER>
__device__ __forceinline__ void flush_node(float* acc, float den, int cur, int f, int lane,
                                           const float* __restrict__ bias,
                                           const float* __restrict__ bng,
                                           const float* __restrict__ bnb,
                                           const float* __restrict__ bnm,
                                           const float* __restrict__ bnv,
                                           void* __restrict__ outp) {
    float inv = 1.f / den;
    #pragma unroll
    for (int k = 0; k < 4; ++k) acc[k] *= inv;

    if constexpr (LAYER == 1) {
        int d0 = f * 256 + lane * 4;
        u32 r01, r23;
        {
            float v0 = acc[0] + bias[d0 + 0];
            float v1 = acc[1] + bias[d0 + 1];
            float v2 = acc[2] + bias[d0 + 2];
            float v3 = acc[3] + bias[d0 + 3];
            v0 = v0 > 0.f ? v0 : expm1f(v0);
            v1 = v1 > 0.f ? v1 : expm1f(v1);
            v2 = v2 > 0.f ? v2 : expm1f(v2);
            v3 = v3 > 0.f ? v3 : expm1f(v3);
            v0 = (v0 - bnm[d0 + 0]) * rsqrtf(bnv[d0 + 0] + EPS_BN) * bng[d0 + 0] + bnb[d0 + 0];
            v1 = (v1 - bnm[d0 + 1]) * rsqrtf(bnv[d0 + 1] + EPS_BN) * bng[d0 + 1] + bnb[d0 + 1];
            v2 = (v2 - bnm[d0 + 2]) * rsqrtf(bnv[d0 + 2] + EPS_BN) * bng[d0 + 2] + bnb[d0 + 2];
            v3 = (v3 - bnm[d0 + 3]) * rsqrtf(bnv[d0 + 3] + EPS_BN) * bng[d0 + 3] + bnb[d0 + 3];
            __hip_bfloat16 b0 = __float2bfloat16(v0), b1 = __float2bfloat16(v1);
            __hip_bfloat16 b2 = __float2bfloat16(v2), b3 = __float2bfloat16(v3);
            r01 = (u32)*(unsigned short*)&b0 | ((u32)*(unsigned short*)&b1 << 16);
            r23 = (u32)*(unsigned short*)&b2 | ((u32)*(unsigned short*)&b3 << 16);
        }
        uint2 pk; pk.x = r01; pk.y = r23;
        *(uint2*)((__hip_bfloat16*)outp + (size_t)cur * DD1 + d0) = pk;
    } else {
        // sum over the 8 heads held by this wave (lane groups stride 8)
        #pragma unroll
        for (int k = 0; k < 4; ++k) {
            acc[k] += __shfl_xor(acc[k], 8, 64);
            acc[k] += __shfl_xor(acc[k], 16, 64);
            acc[k] += __shfl_xor(acc[k], 32, 64);
        }
        if (lane < 8) {
            floatx4 pk;
            #pragma unroll
            for (int k = 0; k < 4; ++k) pk[k] = acc[k] * (1.f / NH);
            *(floatx4*)((float*)outp + ((size_t)cur * 7 + f) * OC + lane * 4) = pk;
        }
    }
    acc[0] = acc[1] = acc[2] = acc[3] = 0.f;
}

// ---------------- fused streaming aggregation with ONLINE SOFTMAX ----------------
// wave = (slice f in [0,7), node group of GRP nodes). Lane covers 4 fp8 features
// at byte offset f*256 + lane*4, head = f*8 + (lane>>3). Per edge: gather h row
// u32 + as[src][head]; online max/den rescale; flush (divide by den) at bounds.
template <int LAYER>
__global__ __launch_bounds__(256) void attn_aggregate(const int* __restrict__ rowptr,
                                                      const int* __restrict__ csr_src,
                                                      const float* __restrict__ as_,
                                                      const float* __restrict__ ad_,
                                                      const unsigned char* __restrict__ h8,
                                                      const float* __restrict__ bias,
                                                      const float* __restrict__ bng,
                                                      const float* __restrict__ bnb,
                                                      const float* __restrict__ bnm,
                                                      const float* __restrict__ bnv,
                                                      void* __restrict__ outp) {
    const int wv = threadIdx.x >> 6, lane = threadIdx.x & 63;
    const int w = blockIdx.x * 4 + wv;
    const int NWAVES = 7 * (NN / GRP);
    if (w >= NWAVES) return;
    const int f  = w % 7;             // feature slice (256 B of the 1792-B row)
    const int g  = w / 7;             // node group
    const int n0 = g * GRP;
    const int off  = f * 256 + lane * 4;
    const int head = f * 8 + (lane >> 3);

    const int e0 = rowptr[n0], e1 = rowptr[n0 + GRP];
    int cur = n0;
    int bound = rowptr[n0 + 1];
    float adv = ad_[(size_t)cur * NH + head];

    float acc[4] = {0.f, 0.f, 0.f, 0.f};
    float m = -1e30f, den = 0.f;

    for (int e = e0; e < e1; e += EB) {
        u32   hv[EB];
        float sv[EB];
        // unconditional clamp-padded loads: EB independent chains in flight
        #pragma unroll
        for (int i = 0; i < EB; ++i) {
            int idx = (e + i < e1) ? e + i : e1 - 1;
            int s = csr_src[idx];
            hv[i] = *(const u32*)(h8 + (size_t)s * DD1 + off);
            sv[i] = as_[(size_t)s * NH + head];
        }
        #pragma unroll
        for (int i = 0; i < EB; ++i) {
            if (e + i >= e1) break;                 // tail padding: skip
            if (e + i >= bound) {                   // crossed into next node
                flush_node<LAYER>(acc, den, cur, f, lane, bias, bng, bnb, bnm, bnv, outp);
                ++cur;
                bound = rowptr[cur + 1];
                adv = ad_[(size_t)cur * NH + head];
                m = -1e30f; den = 0.f;
            }
            float lr = sv[i] + adv;
            lr = lr > 0.f ? lr : 0.2f * lr;         // leaky_relu
            float wgt;
            if (lr > m) {                           // new max: rescale history
                float scale = __expf(m - lr);
                den = den * scale + 1.f;
                #pragma unroll
                for (int k = 0; k < 4; ++k) acc[k] *= scale;
                m = lr;
                wgt = 1.f;
            } else {
                wgt = __expf(lr - m);
                den += wgt;
            }
            fma_fp8x4(hv[i], wgt, acc);
        }
    }
    flush_node<LAYER>(acc, den, cur, f, lane, bias, bng, bnb, bnm, bnv, outp);
}

// ---------------- mean pool: sum 7 slice-partials, atomic into graph sums ----------------
__global__ __launch_bounds__(256) void pool_kernel(const float* __restrict__ h2part,
                                                   const int* __restrict__ batch,
                                                   float* __restrict__ sums,
                                                   float* __restrict__ cnt) {
    int gid = blockIdx.x * 256 + threadIdx.x;
    if (gid >= NN * OC) return;
    int node = gid >> 5, ch = gid & 31;
    float v = 0.f;
    #pragma unroll
    for (int f = 0; f < 7; ++f) v += h2part[((size_t)node * 7 + f) * OC + ch];
    int g = batch[node];
    atomicAdd(&sums[g * OC + ch], v);
    if (ch == 0) atomicAdd(&cnt[g], 1.0f);
}

// final: pooled = sums/cnt; v = BN2(pooled + b2); out = v @ lin_w + lin_b
__global__ __launch_bounds__(128) void final_kernel(const float* __restrict__ sums,
                                                    const float* __restrict__ cnt,
                                                    const float* __restrict__ b2,
                                                    const float* __restrict__ bn2g,
                                                    const float* __restrict__ bn2b,
                                                    const float* __restrict__ bn2m,
                                                    const float* __restrict__ bn2v,
                                                    const float* __restrict__ lin_w,
                                                    const float* __restrict__ lin_b,
                                                    float* __restrict__ out) {
    int t = threadIdx.x;
    if (t >= NG * 2) return;
    int g = t >> 1, c = t & 1;
    float invc = 1.f / fmaxf(cnt[g], 1.f);
    float acc = lin_b[c];
    #pragma unroll
    for (int o = 0; o < OC; ++o) {
        float pooled = sums[g * OC + o] * invc + b2[o];
        float v = (pooled - bn2m[o]) * rsqrtf(bn2v[o] + EPS_BN) * bn2g[o] + bn2b[o];
        acc += v * lin_w[o * 2 + c];
    }
    out[t] = acc;
}

// ---------------- host-side launch ----------------
extern "C" void kernel_launch(void* const* d_in, const int* in_sizes, int n_in,
                              void* d_out, int out_size, void* d_ws, size_t ws_size,
                              hipStream_t stream) {
    const float* x    = (const float*)d_in[0];
    const int*   ei   = (const int*)d_in[1];
    const int*   bat  = (const int*)d_in[2];
    const float* W1   = (const float*)d_in[3];
    const float* at_s1 = (const float*)d_in[4];
    const float* at_d1 = (const float*)d_in[5];
    const float* b1   = (const float*)d_in[6];
    const float* bn1g = (const float*)d_in[7];
    const float* bn1b = (const float*)d_in[8];
    const float* bn1m = (const float*)d_in[9];
    const float* bn1v = (const float*)d_in[10];
    const float* W2   = (const float*)d_in[11];
    const float* at_s2 = (const float*)d_in[12];
    const float* at_d2 = (const float*)d_in[13];
    const float* b2   = (const float*)d_in[14];
    const float* bn2g = (const float*)d_in[15];
    const float* bn2b = (const float*)d_in[16];
    const float* bn2m = (const float*)d_in[17];
    const float* bn2v = (const float*)d_in[18];
    const float* linw = (const float*)d_in[19];
    const float* linb = (const float*)d_in[20];
    float* out = (float*)d_out;

    char* wsp = (char*)d_ws;
    auto alloc = [&](size_t bytes) -> void* {
        void* p = (void*)wsp;
        wsp += (bytes + 255) & ~(size_t)255;
        return p;
    };
    unsigned char*  h8  = (unsigned char*)alloc((size_t)NN * DD1);      // fp8 gemm output
    __hip_bfloat16* h1p = (__hip_bfloat16*)alloc((size_t)NN * DD1 * 2); // agg1 out (gemm2 A)
    __hip_bfloat16* xb  = (__hip_bfloat16*)alloc((size_t)NN * NF * 2);
    __hip_bfloat16* w1t = (__hip_bfloat16*)alloc((size_t)DD1 * NF * 2);
    __hip_bfloat16* w2t = (__hip_bfloat16*)alloc((size_t)DD1 * DD1 * 2);
    float* asb   = (float*)alloc((size_t)NN * NH * 4);
    float* adb   = (float*)alloc((size_t)NN * NH * 4);
    int*   deg   = (int*)alloc((size_t)NN * 4);
    int*   rowp  = (int*)alloc((size_t)(NN + 1) * 4);
    int*   curs  = (int*)alloc((size_t)NN * 4);
    int*   csr   = (int*)alloc((size_t)ETOT * 4);
    float* h2part = (float*)alloc((size_t)NN * 7 * OC * 4);
    float* sums  = (float*)alloc((size_t)(NG * OC + NG) * 4);
    float* cnt   = sums + NG * OC;

    hipMemsetAsync(deg, 0, (size_t)NN * 4, stream);
    hipMemsetAsync(sums, 0, (size_t)(NG * OC + NG) * 4, stream);

    cast_bf16_kernel<<<(NN * NF + 255) / 256, 256, 0, stream>>>(x, xb, NN * NF);
    transpose_cast_kernel<<<dim3(DD1 / 32, NF / 32), 256, 0, stream>>>(W1, w1t, NF, DD1);
    transpose_cast_kernel<<<dim3(DD1 / 32, DD1 / 32), 256, 0, stream>>>(W2, w2t, DD1, DD1);
    hist_kernel<<<(ETOT + 255) / 256, 256, 0, stream>>>(ei, deg);
    scan_kernel<<<1, 1024, 0, stream>>>(deg, rowp, curs);
    scatter_kernel<<<(ETOT + 255) / 256, 256, 0, stream>>>(ei, curs, csr);

    const int AGG_BLOCKS = (7 * (NN / GRP) + 3) / 4;
    const int NBY256 = (NN + 255) / 256;                   // 79
    const int GEMM_BLOCKS = NBY256 * (DD1 / 256);          // 553

    // layer 1
    gemm_256<<<GEMM_BLOCKS, 512, 0, stream>>>(xb, w1t, h8, NN, DD1, NF);
    attn_score<<<NN / 4, 256, 0, stream>>>(h8, at_s1, at_d1, asb, adb);
    attn_aggregate<1><<<AGG_BLOCKS, 256, 0, stream>>>(rowp, csr, asb, adb, h8, b1, bn1g, bn1b, bn1m, bn1v, (void*)h1p);

    // layer 2
    gemm_256<<<GEMM_BLOCKS, 512, 0, stream>>>(h1p, w2t, h8, NN, DD1, DD1);
    attn_score<<<NN / 4, 256, 0, stream>>>(h8, at_s2, at_d2, asb, adb);
    attn_aggregate<2><<<AGG_BLOCKS, 256, 0, stream>>>(rowp, csr, asb, adb, h8, b2, bn2g, bn2b, bn2m, bn2v, (void*)h2part);

    pool_kernel<<<(NN * OC) / 256, 256, 0, stream>>>(h2part, bat, sums, cnt);
    final_kernel<<<1, 128, 0, stream>>>(sums, cnt, b2, bn2g, bn2b, bn2m, bn2v, linw, linb, out);
}

// Round 2
// 737.166 us; speedup vs baseline: 1.0299x; 1.0299x over previous
//
#include <hip/hip_runtime.h>
#include <hip/hip_bf16.h>
#include <hip/hip_fp8.h>
#include <cstdint>
#include <cstddef>

// Problem constants
#define NN     20000     // nodes
#define NF     128       // in features
#define NH     56        // heads
#define OC     32        // out channels per head
#define DD1    1792      // NH*OC
#define NE     100000    // edges (before self loops)
#define ETOT   120000    // edges + self loops
#define NG     50        // graphs
#define EPS_BN 1e-5f
#define GRP    16        // nodes per wave in aggregate
#define EB     16        // edge batch (aggregate loads in flight)

typedef __bf16 bf16x8 __attribute__((ext_vector_type(8)));
typedef float  floatx4 __attribute__((ext_vector_type(4)));
typedef float  floatx2 __attribute__((ext_vector_type(2)));
typedef unsigned int u32;
typedef __attribute__((address_space(1))) u32 gu32;
typedef __attribute__((address_space(3))) u32 lu32;

__device__ __forceinline__ void async_copy16(void* lds, const void* g) {
    __builtin_amdgcn_global_load_lds((gu32*)const_cast<void*>(g), (lu32*)lds, 16, 0, 0);
}

// decode 4 fp8 (e4m3, packed in u32) to 4 floats (HW cvt when available)
__device__ __forceinline__ void dec_fp8x4(u32 u, float* v) {
#if __has_builtin(__builtin_amdgcn_cvt_pk_f32_fp8)
    floatx2 lo = __builtin_amdgcn_cvt_pk_f32_fp8(u, false);
    floatx2 hi = __builtin_amdgcn_cvt_pk_f32_fp8(u, true);
    v[0] = lo[0]; v[1] = lo[1]; v[2] = hi[0]; v[3] = hi[1];
#else
    #pragma unroll
    for (int b = 0; b < 4; ++b) {
        __hip_fp8_e4m3 t;
        t.__x = (u >> (8 * b)) & 0xff;
        v[b] = (float)t;
    }
#endif
}

__device__ __forceinline__ void fma_fp8x4(u32 u, float a, float* acc) {
    float v[4];
    dec_fp8x4(u, v);
    #pragma unroll
    for (int b = 0; b < 4; ++b) acc[b] += a * v[b];
}

// ---------------- elementwise cast fp32 -> bf16 ----------------
__global__ __launch_bounds__(256) void cast_bf16_kernel(const float* __restrict__ in,
                                                        __hip_bfloat16* __restrict__ out, int n) {
    int i = blockIdx.x * 256 + threadIdx.x;
    if (i < n) out[i] = __float2bfloat16(in[i]);
}

// ---------------- tiled transpose + cast: in[R][C] f32 -> out[C][R] bf16 ----------------
__global__ __launch_bounds__(256) void transpose_cast_kernel(const float* __restrict__ in,
                                                             __hip_bfloat16* __restrict__ out,
                                                             int R, int C) {
    __shared__ float tile[32][33];
    int c0 = blockIdx.x * 32, r0 = blockIdx.y * 32;
    int tx = threadIdx.x & 31, ty = threadIdx.x >> 5;   // ty in 0..7
    #pragma unroll
    for (int i = 0; i < 32; i += 8) {
        int r = r0 + ty + i, c = c0 + tx;
        if (r < R && c < C) tile[ty + i][tx] = in[(size_t)r * C + c];
    }
    __syncthreads();
    #pragma unroll
    for (int i = 0; i < 32; i += 8) {
        int c = c0 + ty + i, r = r0 + tx;
        if (c < C && r < R) out[(size_t)c * R + r] = __float2bfloat16(tile[tx][ty + i]);
    }
}

// ---------------- CSR build: histogram / scan / scatter ----------------
__global__ __launch_bounds__(256) void hist_kernel(const int* __restrict__ ei, int* __restrict__ deg) {
    int i = blockIdx.x * 256 + threadIdx.x;
    if (i >= ETOT) return;
    int dst = (i < NE) ? ei[NE + i] : (i - NE);
    atomicAdd(&deg[dst], 1);
}

__global__ __launch_bounds__(1024) void scan_kernel(const int* __restrict__ deg,
                                                    int* __restrict__ rowptr,
                                                    int* __restrict__ cursor) {
    __shared__ int buf[1024];
    int t = threadIdx.x;
    const int CH = (NN + 1023) >> 10;   // 20
    int base = t * CH;
    int s = 0;
    for (int j = 0; j < CH; ++j) { int idx = base + j; if (idx < NN) s += deg[idx]; }
    buf[t] = s;
    __syncthreads();
    for (int off = 1; off < 1024; off <<= 1) {
        int v = (t >= off) ? buf[t - off] : 0;
        __syncthreads();
        buf[t] += v;
        __syncthreads();
    }
    int run = buf[t] - s;   // exclusive
    for (int j = 0; j < CH; ++j) {
        int idx = base + j;
        if (idx < NN) { rowptr[idx] = run; cursor[idx] = run; run += deg[idx]; }
    }
    if (t == 1023) rowptr[NN] = buf[1023];
}

__global__ __launch_bounds__(256) void scatter_kernel(const int* __restrict__ ei,
                                                      int* __restrict__ cursor,
                                                      int* __restrict__ csr_src) {
    int i = blockIdx.x * 256 + threadIdx.x;
    if (i >= ETOT) return;
    int s, d;
    if (i < NE) { s = ei[i]; d = ei[NE + i]; } else { s = i - NE; d = i - NE; }
    int pos = atomicAdd(&cursor[d], 1);
    csr_src[pos] = s;
}

// ---------------- bf16 MFMA GEMM, 256x256 tile, 8-phase m201 schedule ----------------
// 8 waves (2M x 4N), BK=64, 2 LDS buffers (2 x 64 KiB). Per K=128 iteration: 8 phases,
// each = { ds-read register subtile || stage ONE 16KB half-tile (2 global_load_lds x16B)
//          -> s_barrier -> setprio(1) 16 MFMA setprio(0) -> s_barrier }.
// vmcnt(6) ONLY at phases 4 and 8 (3 half-tiles = 6 loads in flight, never drained: T4).
// Stage placement: each region staged in/after the phase of its LAST ds_reads
// (B0@P2, B1@P3, A0@P4, A1@P5 for buf0; B0@P6, B1@P7, A0@P8, A1@next-P1 for buf1),
// so overwrite races are bounded by vmem latency >> ds latency; P5/P1 stages are
// issue-after-consumption-barrier (fully safe). Tail: per-buffer identical-data
// restage (t -= 2) keeps vmcnt accounting uniform and races benign.
// LDS swizzle: chunk c of row r stored at c ^ (r&7) (8 x 16B chunks per 128B row);
// quarter-wave reads land 2 lanes/bank = conflict-free (measured 0 in prior rounds).
__global__ __launch_bounds__(512, 2) void gemm_256(const __hip_bfloat16* __restrict__ A,
                                                   const __hip_bfloat16* __restrict__ Bt,
                                                   unsigned char* __restrict__ C8,
                                                   int M, int N, int K) {
    __shared__ __align__(16) unsigned short lds[2][32768];  // per buf: A[256][64] | B[256][64]
    const int tid  = threadIdx.x;
    const int lane = tid & 63, wave = tid >> 6;
    const int wm = wave >> 2, wn = wave & 3;     // 2 x 4 wave grid; per-wave C: 128 x 64

    const int nbx = N >> 8;                      // 7
    const int nby = (M + 255) >> 8;              // 79
    const int nwg = nbx * nby;                   // 553
    // bijective XCD swizzle (m204): contiguous wg chunk per XCD; bx fastest => A-panel L2 locality
    const int q = nwg >> 3, r = nwg & 7;
    const int xcd = blockIdx.x & 7, bidx = blockIdx.x >> 3;
    const int wg = (xcd < r ? xcd * (q + 1) : r * (q + 1) + (xcd - r) * q) + bidx;
    const int by = wg / nbx, bx = wg - by * nbx;
    const int m0 = by << 8, n0 = bx << 8;

    const int NT = K >> 6;                       // K-tiles of 64: 28 (L2) / 2 (L1)
    const int NI = NT >> 1;                      // iterations: 14 / 1

    const int qq = lane >> 4, rr = lane & 15;
    const int axr = rr & 7;

    // stage one 128-row half of A (mat=0) or B (mat=1) of K-tile kt into buf b
    auto stageH = [&](int kt, int mat, int half, int b) {
        const __hip_bfloat16* src = mat ? Bt : A;
        const int lim = (mat ? N : M) - 1;
        const int base0 = mat ? n0 : m0;
        #pragma unroll
        for (int i = 0; i < 2; ++i) {
            int slot = i * 512 + tid;            // 0..1023, 16B each (linear LDS dest)
            int rl = slot >> 3, pch = slot & 7;
            int row = half * 128 + rl;
            int lc = pch ^ (rl & 7);             // pre-swizzled global source (rule #21)
            int gr = base0 + row; if (gr > lim) gr = lim;
            async_copy16(&lds[b][(mat << 14) + (half << 13) + slot * 8],
                         src + (size_t)gr * K + (kt << 6) + lc * 8);
        }
    };

    floatx4 zero = {0.f, 0.f, 0.f, 0.f};
    floatx4 acc[8][4];
    #pragma unroll
    for (int i = 0; i < 8; ++i)
        #pragma unroll
        for (int jj = 0; jj < 4; ++jj) acc[i][jj] = zero;

    bf16x8 aF[4][2], bA[2][2], bB[2][2];

    auto loadA = [&](int b, int mg) {            // m-frag group mg: rows wm*128 + (mg*4+mf)*16
        #pragma unroll
        for (int mf = 0; mf < 4; ++mf)
            #pragma unroll
            for (int s = 0; s < 2; ++s) {
                int row = wm * 128 + (mg * 4 + mf) * 16 + rr;
                int pch = (s * 4 + qq) ^ axr;
                aF[mf][s] = *(const bf16x8*)&lds[b][row * 64 + pch * 8];
            }
    };
    auto loadB = [&](int b, bf16x8 (&bF)[2][2], int ng) {
        #pragma unroll
        for (int nf = 0; nf < 2; ++nf)
            #pragma unroll
            for (int s = 0; s < 2; ++s) {
                int row = wn * 64 + (ng * 2 + nf) * 16 + rr;
                int pch = (s * 4 + qq) ^ axr;
                bF[nf][s] = *(const bf16x8*)&lds[b][16384 + row * 64 + pch * 8];
            }
    };
    auto mfmaQ = [&](int mg, int ng, bf16x8 (&bF)[2][2]) {   // 16 MFMA quadrant
        __builtin_amdgcn_s_setprio(1);
        #pragma unroll
        for (int mf = 0; mf < 4; ++mf)
            #pragma unroll
            for (int nf = 0; nf < 2; ++nf)
                #pragma unroll
                for (int s = 0; s < 2; ++s)
                    acc[mg * 4 + mf][ng * 2 + nf] = __builtin_amdgcn_mfma_f32_16x16x32_bf16(
                        aF[mf][s], bF[nf][s], acc[mg * 4 + mf][ng * 2 + nf], 0, 0, 0);
        __builtin_amdgcn_s_setprio(0);
    };

#define SB0 __builtin_amdgcn_sched_barrier(0)
#define GBAR do { SB0; __builtin_amdgcn_s_barrier(); SB0; } while (0)

    auto clampT = [&](int t) { while (t >= NT) t -= 2; return t; };

    // prologue: tile0 (4 halves) -> buf0; tile1 B0,B1,A0 -> buf1 (A1 completes at P1)
    stageH(0, 0, 0, 0); stageH(0, 0, 1, 0); stageH(0, 1, 0, 0); stageH(0, 1, 1, 0);
    stageH(1, 1, 0, 1); stageH(1, 1, 1, 1); stageH(1, 0, 0, 1);
    SB0;
    asm volatile("s_waitcnt vmcnt(6)" ::: "memory");         // tile0 landed
    GBAR;

    for (int i = 0; i < NI; ++i) {
        const int tb1 = clampT(2 * i + 1);   // current buf1 tile (its A1 staged at P1)
        const int tn0 = clampT(2 * i + 2);   // next buf0 tile
        const int tn1 = clampT(2 * i + 3);   // next buf1 tile

        // P1: reads buf0 aF(m0-3)+bA; stage tb1 A1 -> buf1 (buf1 reads done prev P8)
        loadA(0, 0); loadB(0, bA, 0);
        stageH(tb1, 0, 1, 1);
        GBAR; mfmaQ(0, 0, bA); GBAR;

        // P2: reads bB(buf0); stage tn0 B0 -> buf0 (B0 last reads issued this phase)
        loadB(0, bB, 1);
        stageH(tn0, 1, 0, 0);
        GBAR; mfmaQ(0, 1, bB); GBAR;

        // P3: reads aF(m4-7, buf0); stage tn0 B1 -> buf0 (B1 reads done P2)
        loadA(0, 1);
        stageH(tn0, 1, 1, 0);
        GBAR; mfmaQ(1, 1, bB); GBAR;

        // P4: no reads; stage tn0 A0 -> buf0 (A0 reads issued P3); vmcnt(6): tile tb1 complete
        stageH(tn0, 0, 0, 0);
        SB0;
        asm volatile("s_waitcnt vmcnt(6)" ::: "memory");
        GBAR; mfmaQ(1, 0, bA); GBAR;

        // P5: reads buf1 aF(m0-3)+bA; stage tn0 A1 -> buf0 (buf0 reads done P4: safe)
        loadA(1, 0); loadB(1, bA, 0);
        stageH(tn0, 0, 1, 0);
        GBAR; mfmaQ(0, 0, bA); GBAR;

        // P6: reads bB(buf1); stage tn1 B0 -> buf1
        loadB(1, bB, 1);
        stageH(tn1, 1, 0, 1);
        GBAR; mfmaQ(0, 1, bB); GBAR;

        // P7: reads aF(m4-7, buf1); stage tn1 B1 -> buf1
        loadA(1, 1);
        stageH(tn1, 1, 1, 1);
        GBAR; mfmaQ(1, 1, bB); GBAR;

        // P8: stage tn1 A0 -> buf1; vmcnt(6): tile tn0 complete before next P1
        stageH(tn1, 0, 0, 1);
        SB0;
        asm volatile("s_waitcnt vmcnt(6)" ::: "memory");
        GBAR; mfmaQ(1, 0, bA); GBAR;
    }
#undef GBAR
#undef SB0

    // epilogue: fp8 quantize + store
    #pragma unroll
    for (int mt = 0; mt < 8; ++mt) {
        #pragma unroll
        for (int r4 = 0; r4 < 4; ++r4) {
            int rowc = m0 + wm * 128 + mt * 16 + (lane >> 4) * 4 + r4;
            if (rowc < M) {
                float v0 = acc[mt][0][r4], v1 = acc[mt][1][r4];
                float v2 = acc[mt][2][r4], v3 = acc[mt][3][r4];
                unsigned char q8[4];
#if __has_builtin(__builtin_amdgcn_cvt_pk_fp8_f32)
                u32 p01 = (u32)__builtin_amdgcn_cvt_pk_fp8_f32(v0, v1, 0, false);
                u32 p23 = (u32)__builtin_amdgcn_cvt_pk_fp8_f32(v2, v3, 0, false);
                q8[0] = p01 & 0xff; q8[1] = (p01 >> 8) & 0xff;
                q8[2] = p23 & 0xff; q8[3] = (p23 >> 8) & 0xff;
#else
                { __hip_fp8_e4m3 t0(v0), t1(v1), t2(v2), t3(v3);
                  q8[0] = t0.__x; q8[1] = t1.__x; q8[2] = t2.__x; q8[3] = t3.__x; }
#endif
                #pragma unroll
                for (int nt = 0; nt < 4; ++nt) {
                    int col = n0 + wn * 64 + nt * 16 + (lane & 15);
                    C8[(size_t)rowc * N + col] = q8[nt];
                }
            }
        }
    }
}

// ---------------- attention scores from fp8 h: as/ad[n,h] = sum_o h[n,h,o]*att[h,o] ----------------
__global__ __launch_bounds__(256) void attn_score(const unsigned char* __restrict__ h8,
                                                  const float* __restrict__ att_src,
                                                  const float* __restrict__ att_dst,
                                                  float* __restrict__ as_,
                                                  float* __restrict__ ad_) {
    int wave = threadIdx.x >> 6, lane = threadIdx.x & 63;
    int node = blockIdx.x * 4 + wave;
    if (node >= NN || lane >= NH) return;
    const uint2* hp = (const uint2*)(h8 + (size_t)node * DD1 + lane * OC);   // 32 B / head
    float s = 0.f, d = 0.f;
    #pragma unroll
    for (int jj = 0; jj < 4; ++jj) {
        uint2 u2 = hp[jj];
        u32 us[2] = {u2.x, u2.y};
        #pragma unroll
        for (int w = 0; w < 2; ++w) {
            float v[4];
            dec_fp8x4(us[w], v);
            #pragma unroll
            for (int b = 0; b < 4; ++b) {
                int o = jj * 8 + w * 4 + b;
                s += v[b] * att_src[lane * OC + o];
                d += v[b] * att_dst[lane * OC + o];
            }
        }
    }
    as_[(size_t)node * NH + lane] = s;
    ad_[(size_t)node * NH + lane] = d;
}

// ---------------- node-boundary flush for the fused streaming aggregate ----------------
// acc holds UNNORMALIZED weighted sums; divide by den here.
// LAYER==1: bf16 h1p[cur][slice] = BN1(ELU(acc/den + b1))
// LAYER==2: head-reduce in-wave, write per-slice partial (non-atomic) to h2part[cur][f][32]
template <int LAYER>
__device__ __forceinline__ void flush_node(float* acc, float den, int cur, int f, int lane,
                                           const float* __restrict__ bias,
                                           const float* __restrict__ bng,
                                           const float* __restrict__ bnb,
                                           const float* __restrict__ bnm,
                                           const float* __restrict__ bnv,
                                           void* __restrict__ outp) {
    float inv = 1.f / den;
    #pragma unroll
    for (int k = 0; k < 4; ++k) acc[k] *= inv;

    if constexpr (LAYER == 1) {
        int d0 = f * 256 + lane * 4;
        u32 r01, r23;
        {
            float v0 = acc[0] + bias[d0 + 0];
            float v1 = acc[1] + bias[d0 + 1];
            float v2 = acc[2] + bias[d0 + 2];
            float v3 = acc[3] + bias[d0 + 3];
            v0 = v0 > 0.f ? v0 : expm1f(v0);
            v1 = v1 > 0.f ? v1 : expm1f(v1);
            v2 = v2 > 0.f ? v2 : expm1f(v2);
            v3 = v3 > 0.f ? v3 : expm1f(v3);
            v0 = (v0 - bnm[d0 + 0]) * rsqrtf(bnv[d0 + 0] + EPS_BN) * bng[d0 + 0] + bnb[d0 + 0];
            v1 = (v1 - bnm[d0 + 1]) * rsqrtf(bnv[d0 + 1] + EPS_BN) * bng[d0 + 1] + bnb[d0 + 1];
            v2 = (v2 - bnm[d0 + 2]) * rsqrtf(bnv[d0 + 2] + EPS_BN) * bng[d0 + 2] + bnb[d0 + 2];
            v3 = (v3 - bnm[d0 + 3]) * rsqrtf(bnv[d0 + 3] + EPS_BN) * bng[d0 + 3] + bnb[d0 + 3];
            __hip_bfloat16 b0 = __float2bfloat16(v0), b1 = __float2bfloat16(v1);
            __hip_bfloat16 b2 = __float2bfloat16(v2), b3 = __float2bfloat16(v3);
            r01 = (u32)*(unsigned short*)&b0 | ((u32)*(unsigned short*)&b1 << 16);
            r23 = (u32)*(unsigned short*)&b2 | ((u32)*(unsigned short*)&b3 << 16);
        }
        uint2 pk; pk.x = r01; pk.y = r23;
        *(uint2*)((__hip_bfloat16*)outp + (size_t)cur * DD1 + d0) = pk;
    } else {
        // sum over the 8 heads held by this wave (lane groups stride 8)
        #pragma unroll
        for (int k = 0; k < 4; ++k) {
            acc[k] += __shfl_xor(acc[k], 8, 64);
            acc[k] += __shfl_xor(acc[k], 16, 64);
            acc[k] += __shfl_xor(acc[k], 32, 64);
        }
        if (lane < 8) {
            floatx4 pk;
            #pragma unroll
            for (int k = 0; k < 4; ++k) pk[k] = acc[k] * (1.f / NH);
            *(floatx4*)((float*)outp + ((size_t)cur * 7 + f) * OC + lane * 4) = pk;
        }
    }
    acc[0] = acc[1] = acc[2] = acc[3] = 0.f;
}

// ---------------- fused streaming aggregation with ONLINE SOFTMAX ----------------
// wave = (slice f in [0,7), node group of GRP nodes). Lane covers 4 fp8 features
// at byte offset f*256 + lane*4, head = f*8 + (lane>>3). Per edge: gather h row
// u32 + as[src][head]; online max/den rescale; flush (divide by den) at bounds.
template <int LAYER>
__global__ __launch_bounds__(256) void attn_aggregate(const int* __restrict__ rowptr,
                                                      const int* __restrict__ csr_src,
                                                      const float* __restrict__ as_,
                                                      const float* __restrict__ ad_,
                                                      const unsigned char* __restrict__ h8,
                                                      const float* __restrict__ bias,
                                                      const float* __restrict__ bng,
                                                      const float* __restrict__ bnb,
                                                      const float* __restrict__ bnm,
                                                      const float* __restrict__ bnv,
                                                      void* __restrict__ outp) {
    const int wv = threadIdx.x >> 6, lane = threadIdx.x & 63;
    const int w = blockIdx.x * 4 + wv;
    const int NWAVES = 7 * (NN / GRP);
    if (w >= NWAVES) return;
    const int f  = w % 7;             // feature slice (256 B of the 1792-B row)
    const int g  = w / 7;             // node group
    const int n0 = g * GRP;
    const int off  = f * 256 + lane * 4;
    const int head = f * 8 + (lane >> 3);

    const int e0 = rowptr[n0], e1 = rowptr[n0 + GRP];
    int cur = n0;
    int bound = rowptr[n0 + 1];
    float adv = ad_[(size_t)cur * NH + head];

    float acc[4] = {0.f, 0.f, 0.f, 0.f};
    float m = -1e30f, den = 0.f;

    for (int e = e0; e < e1; e += EB) {
        u32   hv[EB];
        float sv[EB];
        // unconditional clamp-padded loads: EB independent chains in flight
        #pragma unroll
        for (int i = 0; i < EB; ++i) {
            int idx = (e + i < e1) ? e + i : e1 - 1;
            int s = csr_src[idx];
            hv[i] = *(const u32*)(h8 + (size_t)s * DD1 + off);
            sv[i] = as_[(size_t)s * NH + head];
        }
        #pragma unroll
        for (int i = 0; i < EB; ++i) {
            if (e + i >= e1) break;                 // tail padding: skip
            if (e + i >= bound) {                   // crossed into next node
                flush_node<LAYER>(acc, den, cur, f, lane, bias, bng, bnb, bnm, bnv, outp);
                ++cur;
                bound = rowptr[cur + 1];
                adv = ad_[(size_t)cur * NH + head];
                m = -1e30f; den = 0.f;
            }
            float lr = sv[i] + adv;
            lr = lr > 0.f ? lr : 0.2f * lr;         // leaky_relu
            float wgt;
            if (lr > m) {                           // new max: rescale history
                float scale = __expf(m - lr);
                den = den * scale + 1.f;
                #pragma unroll
                for (int k = 0; k < 4; ++k) acc[k] *= scale;
                m = lr;
                wgt = 1.f;
            } else {
                wgt = __expf(lr - m);
                den += wgt;
            }
            fma_fp8x4(hv[i], wgt, acc);
        }
    }
    flush_node<LAYER>(acc, den, cur, f, lane, bias, bng, bnb, bnm, bnv, outp);
}

// ---------------- mean pool: sum 7 slice-partials, atomic into graph sums ----------------
__global__ __launch_bounds__(256) void pool_kernel(const float* __restrict__ h2part,
                                                   const int* __restrict__ batch,
                                                   float* __restrict__ sums,
                                                   float* __restrict__ cnt) {
    int gid = blockIdx.x * 256 + threadIdx.x;
    if (gid >= NN * OC) return;
    int node = gid >> 5, ch = gid & 31;
    float v = 0.f;
    #pragma unroll
    for (int f = 0; f < 7; ++f) v += h2part[((size_t)node * 7 + f) * OC + ch];
    int g = batch[node];
    atomicAdd(&sums[g * OC + ch], v);
    if (ch == 0) atomicAdd(&cnt[g], 1.0f);
}

// final: pooled = sums/cnt; v = BN2(pooled + b2); out = v @ lin_w + lin_b
__global__ __launch_bounds__(128) void final_kernel(const float* __restrict__ sums,
                                                    const float* __restrict__ cnt,
                                                    const float* __restrict__ b2,
                                                    const float* __restrict__ bn2g,
                                                    const float* __restrict__ bn2b,
                                                    const float* __restrict__ bn2m,
                                                    const float* __restrict__ bn2v,
                                                    const float* __restrict__ lin_w,
                                                    const float* __restrict__ lin_b,
                                                    float* __restrict__ out) {
    int t = threadIdx.x;
    if (t >= NG * 2) return;
    int g = t >> 1, c = t & 1;
    float invc = 1.f / fmaxf(cnt[g], 1.f);
    float acc = lin_b[c];
    #pragma unroll
    for (int o = 0; o < OC; ++o) {
        float pooled = sums[g * OC + o] * invc + b2[o];
        float v = (pooled - bn2m[o]) * rsqrtf(bn2v[o] + EPS_BN) * bn2g[o] + bn2b[o];
        acc += v * lin_w[o * 2 + c];
    }
    out[t] = acc;
}

// ---------------- host-side launch ----------------
extern "C" void kernel_launch(void* const* d_in, const int* in_sizes, int n_in,
                              void* d_out, int out_size, void* d_ws, size_t ws_size,
                              hipStream_t stream) {
    const float* x    = (const float*)d_in[0];
    const int*   ei   = (const int*)d_in[1];
    const int*   bat  = (const int*)d_in[2];
    const float* W1   = (const float*)d_in[3];
    const float* at_s1 = (const float*)d_in[4];
    const float* at_d1 = (const float*)d_in[5];
    const float* b1   = (const float*)d_in[6];
    const float* bn1g = (const float*)d_in[7];
    const float* bn1b = (const float*)d_in[8];
    const float* bn1m = (const float*)d_in[9];
    const float* bn1v = (const float*)d_in[10];
    const float* W2   = (const float*)d_in[11];
    const float* at_s2 = (const float*)d_in[12];
    const float* at_d2 = (const float*)d_in[13];
    const float* b2   = (const float*)d_in[14];
    const float* bn2g = (const float*)d_in[15];
    const float* bn2b = (const float*)d_in[16];
    const float* bn2m = (const float*)d_in[17];
    const float* bn2v = (const float*)d_in[18];
    const float* linw = (const float*)d_in[19];
    const float* linb = (const float*)d_in[20];
    float* out = (float*)d_out;

    char* wsp = (char*)d_ws;
    auto alloc = [&](size_t bytes) -> void* {
        void* p = (void*)wsp;
        wsp += (bytes + 255) & ~(size_t)255;
        return p;
    };
    unsigned char*  h8  = (unsigned char*)alloc((size_t)NN * DD1);      // fp8 gemm output
    __hip_bfloat16* h1p = (__hip_bfloat16*)alloc((size_t)NN * DD1 * 2); // agg1 out (gemm2 A)
    __hip_bfloat16* xb  = (__hip_bfloat16*)alloc((size_t)NN * NF * 2);
    __hip_bfloat16* w1t = (__hip_bfloat16*)alloc((size_t)DD1 * NF * 2);
    __hip_bfloat16* w2t = (__hip_bfloat16*)alloc((size_t)DD1 * DD1 * 2);
    float* asb   = (float*)alloc((size_t)NN * NH * 4);
    float* adb   = (float*)alloc((size_t)NN * NH * 4);
    int*   deg   = (int*)alloc((size_t)NN * 4);
    int*   rowp  = (int*)alloc((size_t)(NN + 1) * 4);
    int*   curs  = (int*)alloc((size_t)NN * 4);
    int*   csr   = (int*)alloc((size_t)ETOT * 4);
    float* h2part = (float*)alloc((size_t)NN * 7 * OC * 4);
    float* sums  = (float*)alloc((size_t)(NG * OC + NG) * 4);
    float* cnt   = sums + NG * OC;

    hipMemsetAsync(deg, 0, (size_t)NN * 4, stream);
    hipMemsetAsync(sums, 0, (size_t)(NG * OC + NG) * 4, stream);

    cast_bf16_kernel<<<(NN * NF + 255) / 256, 256, 0, stream>>>(x, xb, NN * NF);
    transpose_cast_kernel<<<dim3(DD1 / 32, NF / 32), 256, 0, stream>>>(W1, w1t, NF, DD1);
    transpose_cast_kernel<<<dim3(DD1 / 32, DD1 / 32), 256, 0, stream>>>(W2, w2t, DD1, DD1);
    hist_kernel<<<(ETOT + 255) / 256, 256, 0, stream>>>(ei, deg);
    scan_kernel<<<1, 1024, 0, stream>>>(deg, rowp, curs);
    scatter_kernel<<<(ETOT + 255) / 256, 256, 0, stream>>>(ei, curs, csr);

    const int AGG_BLOCKS = (7 * (NN / GRP) + 3) / 4;
    const int NBY256 = (NN + 255) / 256;                   // 79
    const int GEMM_BLOCKS = NBY256 * (DD1 / 256);          // 553

    // layer 1
    gemm_256<<<GEMM_BLOCKS, 512, 0, stream>>>(xb, w1t, h8, NN, DD1, NF);
    attn_score<<<NN / 4, 256, 0, stream>>>(h8, at_s1, at_d1, asb, adb);
    attn_aggregate<1><<<AGG_BLOCKS, 256, 0, stream>>>(rowp, csr, asb, adb, h8, b1, bn1g, bn1b, bn1m, bn1v, (void*)h1p);

    // layer 2
    gemm_256<<<GEMM_BLOCKS, 512, 0, stream>>>(h1p, w2t, h8, NN, DD1, DD1);
    attn_score<<<NN / 4, 256, 0, stream>>>(h8, at_s2, at_d2, asb, adb);
    attn_aggregate<2><<<AGG_BLOCKS, 256, 0, stream>>>(rowp, csr, asb, adb, h8, b2, bn2g, bn2b, bn2m, bn2v, (void*)h2part);

    pool_kernel<<<(NN * OC) / 256, 256, 0, stream>>>(h2part, bat, sums, cnt);
    final_kernel<<<1, 128, 0, stream>>>(sums, cnt, b2, bn2g, bn2b, bn2m, bn2v, linw, linb, out);
}

// Round 4
// 716.857 us; speedup vs baseline: 1.0590x; 1.0283x over previous
//
#include <hip/hip_runtime.h>
#include <hip/hip_bf16.h>
#include <hip/hip_fp8.h>
#include <cstdint>
#include <cstddef>

// Problem constants
#define NN     20000     // nodes
#define NF     128       // in features
#define NH     56        // heads
#define OC     32        // out channels per head
#define DD1    1792      // NH*OC
#define NE     100000    // edges (before self loops)
#define ETOT   120000    // edges + self loops
#define NG     50        // graphs
#define EPS_BN 1e-5f
#define GRP    16        // nodes per wave in aggregate
#define EB     16        // edge batch (aggregate loads in flight)

typedef __bf16 bf16x8 __attribute__((ext_vector_type(8)));
typedef float  floatx4 __attribute__((ext_vector_type(4)));
typedef float  floatx2 __attribute__((ext_vector_type(2)));
typedef unsigned int u32;
typedef __attribute__((address_space(1))) u32 gu32;
typedef __attribute__((address_space(3))) u32 lu32;

__device__ __forceinline__ void async_copy16(void* lds, const void* g) {
    __builtin_amdgcn_global_load_lds((gu32*)const_cast<void*>(g), (lu32*)lds, 16, 0, 0);
}

// decode 4 fp8 (e4m3, packed in u32) to 4 floats (HW cvt when available)
__device__ __forceinline__ void dec_fp8x4(u32 u, float* v) {
#if __has_builtin(__builtin_amdgcn_cvt_pk_f32_fp8)
    floatx2 lo = __builtin_amdgcn_cvt_pk_f32_fp8(u, false);
    floatx2 hi = __builtin_amdgcn_cvt_pk_f32_fp8(u, true);
    v[0] = lo[0]; v[1] = lo[1]; v[2] = hi[0]; v[3] = hi[1];
#else
    #pragma unroll
    for (int b = 0; b < 4; ++b) {
        __hip_fp8_e4m3 t;
        t.__x = (u >> (8 * b)) & 0xff;
        v[b] = (float)t;
    }
#endif
}

__device__ __forceinline__ void fma_fp8x4(u32 u, float a, float* acc) {
    float v[4];
    dec_fp8x4(u, v);
    #pragma unroll
    for (int b = 0; b < 4; ++b) acc[b] += a * v[b];
}

// ---------------- elementwise cast fp32 -> bf16 ----------------
__global__ __launch_bounds__(256) void cast_bf16_kernel(const float* __restrict__ in,
                                                        __hip_bfloat16* __restrict__ out, int n) {
    int i = blockIdx.x * 256 + threadIdx.x;
    if (i < n) out[i] = __float2bfloat16(in[i]);
}

// ---------------- tiled transpose + cast: in[R][C] f32 -> out[C][R] bf16 ----------------
__global__ __launch_bounds__(256) void transpose_cast_kernel(const float* __restrict__ in,
                                                             __hip_bfloat16* __restrict__ out,
                                                             int R, int C) {
    __shared__ float tile[32][33];
    int c0 = blockIdx.x * 32, r0 = blockIdx.y * 32;
    int tx = threadIdx.x & 31, ty = threadIdx.x >> 5;   // ty in 0..7
    #pragma unroll
    for (int i = 0; i < 32; i += 8) {
        int r = r0 + ty + i, c = c0 + tx;
        if (r < R && c < C) tile[ty + i][tx] = in[(size_t)r * C + c];
    }
    __syncthreads();
    #pragma unroll
    for (int i = 0; i < 32; i += 8) {
        int c = c0 + ty + i, r = r0 + tx;
        if (c < C && r < R) out[(size_t)c * R + r] = __float2bfloat16(tile[tx][ty + i]);
    }
}

// ---------------- CSR build: histogram / scan / scatter ----------------
__global__ __launch_bounds__(256) void hist_kernel(const int* __restrict__ ei, int* __restrict__ deg) {
    int i = blockIdx.x * 256 + threadIdx.x;
    if (i >= ETOT) return;
    int dst = (i < NE) ? ei[NE + i] : (i - NE);
    atomicAdd(&deg[dst], 1);
}

__global__ __launch_bounds__(1024) void scan_kernel(const int* __restrict__ deg,
                                                    int* __restrict__ rowptr,
                                                    int* __restrict__ cursor) {
    __shared__ int buf[1024];
    int t = threadIdx.x;
    const int CH = (NN + 1023) >> 10;   // 20
    int base = t * CH;
    int s = 0;
    for (int j = 0; j < CH; ++j) { int idx = base + j; if (idx < NN) s += deg[idx]; }
    buf[t] = s;
    __syncthreads();
    for (int off = 1; off < 1024; off <<= 1) {
        int v = (t >= off) ? buf[t - off] : 0;
        __syncthreads();
        buf[t] += v;
        __syncthreads();
    }
    int run = buf[t] - s;   // exclusive
    for (int j = 0; j < CH; ++j) {
        int idx = base + j;
        if (idx < NN) { rowptr[idx] = run; cursor[idx] = run; run += deg[idx]; }
    }
    if (t == 1023) rowptr[NN] = buf[1023];
}

__global__ __launch_bounds__(256) void scatter_kernel(const int* __restrict__ ei,
                                                      int* __restrict__ cursor,
                                                      int* __restrict__ csr_src) {
    int i = blockIdx.x * 256 + threadIdx.x;
    if (i >= ETOT) return;
    int s, d;
    if (i < NE) { s = ei[i]; d = ei[NE + i]; } else { s = i - NE; d = i - NE; }
    int pos = atomicAdd(&cursor[d], 1);
    csr_src[pos] = s;
}

// ---------------- bf16 MFMA GEMM, 192x256 tile, 3-phase-per-K-tile schedule ----------------
// 8 waves (2M x 4N), per-wave C 96x64, BK=64, 2 LDS buffers (A[192][64]+B[256][64] = 56KB each).
// Grid 105x7 = 735 blocks = 2.87/CU -> 3 rounds at 96% CU utilization (vs 553 -> 72%).
// Per K-tile (BK=64), 3 phases, each {ds_reads || stage -> barrier -> MFMA -> barrier}:
//   PhA: read aF g0 (6 b128) + bA (4)          | no stage            | 12 MFMA Q(0,0)
//   PhB: read bB (4)                            | stage B(t+2) 4 ld  | 12 MFMA Q(0,1)
//   PhC: read aF g1 (6)                         | stage A(t+2) 3 ld  | 24 MFMA Q(1,1)+Q(1,0)
// Counted vmcnt(7) ONCE per tile at PhC (7 loads/tile/wave; 14 in flight at the wait ->
// retires exactly tile t+1 before PhA(t+1) reads it; never drained: T4). Stage placement:
// every staged region's last ds_reads are issued in the same or an earlier phase (same
// safety argument as the round-2 passing kernel / m201). Tail: parity-preserving clamp
// (tp -= 2) restages identical data -> benign, uniform vmcnt accounting.
// LDS swizzle: chunk c of 128B row r stored at c ^ (r&7); reads land 2 lanes/bank
// (free); measured 0 conflicts in prior rounds.
__global__ __launch_bounds__(512, 2) void gemm_192(const __hip_bfloat16* __restrict__ A,
                                                   const __hip_bfloat16* __restrict__ Bt,
                                                   unsigned char* __restrict__ C8,
                                                   int M, int N, int K) {
    __shared__ __align__(16) unsigned short lds[2][28672];  // per buf: A[192][64] | B[256][64]
    const int tid  = threadIdx.x;
    const int lane = tid & 63, wave = tid >> 6;
    const int wm = wave >> 2, wn = wave & 3;     // 2 x 4 wave grid; per-wave C: 96 x 64

    const int nbx = N >> 8;                      // 7
    const int nby = (M + 191) / 192;             // 105
    const int nwg = nbx * nby;                   // 735
    // bijective XCD swizzle (m204); bx fastest => A-panel L2 locality within XCD
    const int q = nwg >> 3, r = nwg & 7;
    const int xcd = blockIdx.x & 7, bidx = blockIdx.x >> 3;
    const int wg = (xcd < r ? xcd * (q + 1) : r * (q + 1) + (xcd - r) * q) + bidx;
    const int by = wg / nbx, bx = wg - by * nbx;
    const int m0 = by * 192, n0 = bx << 8;

    const int NT = K >> 6;                       // K-tiles of 64: 28 (L2) / 2 (L1)

    const int qq = lane >> 4, rr = lane & 15;

    // stage A of K-tile kt into buf b: 192 rows x 8 chunks = 1536 slots = 3 loads/thread
    auto stageA = [&](int kt, int b) {
        #pragma unroll
        for (int i = 0; i < 3; ++i) {
            int slot = i * 512 + tid;
            int row = slot >> 3, pch = slot & 7;
            int lc = pch ^ (row & 7);            // pre-swizzled global source (rule #21)
            int gr = m0 + row; if (gr > M - 1) gr = M - 1;
            async_copy16(&lds[b][slot * 8], A + (size_t)gr * K + (kt << 6) + lc * 8);
        }
    };
    // stage B of K-tile kt into buf b: 256 rows x 8 chunks = 2048 slots = 4 loads/thread
    auto stageB = [&](int kt, int b) {
        #pragma unroll
        for (int i = 0; i < 4; ++i) {
            int slot = i * 512 + tid;
            int row = slot >> 3, pch = slot & 7;
            int lc = pch ^ (row & 7);
            async_copy16(&lds[b][12288 + slot * 8], Bt + (size_t)(n0 + row) * K + (kt << 6) + lc * 8);
        }
    };

    floatx4 zero = {0.f, 0.f, 0.f, 0.f};
    floatx4 acc[6][4];
    #pragma unroll
    for (int i = 0; i < 6; ++i)
        #pragma unroll
        for (int jj = 0; jj < 4; ++jj) acc[i][jj] = zero;

    bf16x8 aF[3][2], bA[2][2], bB[2][2];

    auto loadA = [&](int b, int mg) {            // m-group mg: 3 frags, rows wm*96 + mg*48 + mf*16
        #pragma unroll
        for (int mf = 0; mf < 3; ++mf)
            #pragma unroll
            for (int s = 0; s < 2; ++s) {
                int row = wm * 96 + mg * 48 + mf * 16 + rr;
                int pch = (s * 4 + qq) ^ (row & 7);
                aF[mf][s] = *(const bf16x8*)&lds[b][row * 64 + pch * 8];
            }
    };
    auto loadB = [&](int b, bf16x8 (&bF)[2][2], int ng) {
        #pragma unroll
        for (int nf = 0; nf < 2; ++nf)
            #pragma unroll
            for (int s = 0; s < 2; ++s) {
                int row = wn * 64 + (ng * 2 + nf) * 16 + rr;
                int pch = (s * 4 + qq) ^ (row & 7);
                bF[nf][s] = *(const bf16x8*)&lds[b][12288 + row * 64 + pch * 8];
            }
    };
    auto mfmaQ = [&](int mg, int ng, bf16x8 (&bF)[2][2]) {   // 12 MFMA quadrant
        #pragma unroll
        for (int mf = 0; mf < 3; ++mf)
            #pragma unroll
            for (int nf = 0; nf < 2; ++nf)
                #pragma unroll
                for (int s = 0; s < 2; ++s)
                    acc[mg * 3 + mf][ng * 2 + nf] = __builtin_amdgcn_mfma_f32_16x16x32_bf16(
                        aF[mf][s], bF[nf][s], acc[mg * 3 + mf][ng * 2 + nf], 0, 0, 0);
    };

#define SB0 __builtin_amdgcn_sched_barrier(0)
#define GBAR do { SB0; __builtin_amdgcn_s_barrier(); SB0; } while (0)

    // prologue: tiles 0,1 staged (B then A per tile, 7 loads each = 14 in flight)
    stageB(0, 0); stageA(0, 0);
    stageB(1, 1); stageA(1, 1);
    SB0;
    asm volatile("s_waitcnt vmcnt(7)" ::: "memory");         // tile0 landed; tile1 in flight
    GBAR;

    for (int t = 0; t < NT; ++t) {
        const int p = t & 1;
        int tp = t + 2; while (tp >= NT) tp -= 2;            // parity-preserving tail clamp

        // PhA: reads aF g0 + bA (10 ds_reads); no stage
        loadA(p, 0); loadB(p, bA, 0);
        GBAR;
        __builtin_amdgcn_s_setprio(1);
        mfmaQ(0, 0, bA);
        __builtin_amdgcn_s_setprio(0);
        GBAR;

        // PhB: reads bB (4); stage B(t+2) -> buf p (bA-set reads completed PhA; bB issued here)
        loadB(p, bB, 1);
        stageB(tp, p);
        GBAR;
        __builtin_amdgcn_s_setprio(1);
        mfmaQ(0, 1, bB);
        __builtin_amdgcn_s_setprio(0);
        GBAR;

        // PhC: reads aF g1 (6); stage A(t+2) -> buf p; vmcnt(7): tile t+1 fully landed
        loadA(p, 1);
        stageA(tp, p);
        SB0;
        asm volatile("s_waitcnt vmcnt(7)" ::: "memory");
        GBAR;
        __builtin_amdgcn_s_setprio(1);
        mfmaQ(1, 1, bB);
        mfmaQ(1, 0, bA);
        __builtin_amdgcn_s_setprio(0);
        GBAR;
    }
#undef GBAR
#undef SB0

    // epilogue: fp8 quantize + store
    #pragma unroll
    for (int mt = 0; mt < 6; ++mt) {
        #pragma unroll
        for (int r4 = 0; r4 < 4; ++r4) {
            int rowc = m0 + wm * 96 + mt * 16 + (lane >> 4) * 4 + r4;
            if (rowc < M) {
                float v0 = acc[mt][0][r4], v1 = acc[mt][1][r4];
                float v2 = acc[mt][2][r4], v3 = acc[mt][3][r4];
                unsigned char q8[4];
#if __has_builtin(__builtin_amdgcn_cvt_pk_fp8_f32)
                u32 p01 = (u32)__builtin_amdgcn_cvt_pk_fp8_f32(v0, v1, 0, false);
                u32 p23 = (u32)__builtin_amdgcn_cvt_pk_fp8_f32(v2, v3, 0, false);
                q8[0] = p01 & 0xff; q8[1] = (p01 >> 8) & 0xff;
                q8[2] = p23 & 0xff; q8[3] = (p23 >> 8) & 0xff;
#else
                { __hip_fp8_e4m3 t0(v0), t1(v1), t2(v2), t3(v3);
                  q8[0] = t0.__x; q8[1] = t1.__x; q8[2] = t2.__x; q8[3] = t3.__x; }
#endif
                #pragma unroll
                for (int nt = 0; nt < 4; ++nt) {
                    int col = n0 + wn * 64 + nt * 16 + (lane & 15);
                    C8[(size_t)rowc * N + col] = q8[nt];
                }
            }
        }
    }
}

// ---------------- attention scores from fp8 h: as/ad[n,h] = sum_o h[n,h,o]*att[h,o] ----------------
__global__ __launch_bounds__(256) void attn_score(const unsigned char* __restrict__ h8,
                                                  const float* __restrict__ att_src,
                                                  const float* __restrict__ att_dst,
                                                  float* __restrict__ as_,
                                                  float* __restrict__ ad_) {
    int wave = threadIdx.x >> 6, lane = threadIdx.x & 63;
    int node = blockIdx.x * 4 + wave;
    if (node >= NN || lane >= NH) return;
    const uint2* hp = (const uint2*)(h8 + (size_t)node * DD1 + lane * OC);   // 32 B / head
    float s = 0.f, d = 0.f;
    #pragma unroll
    for (int jj = 0; jj < 4; ++jj) {
        uint2 u2 = hp[jj];
        u32 us[2] = {u2.x, u2.y};
        #pragma unroll
        for (int w = 0; w < 2; ++w) {
            float v[4];
            dec_fp8x4(us[w], v);
            #pragma unroll
            for (int b = 0; b < 4; ++b) {
                int o = jj * 8 + w * 4 + b;
                s += v[b] * att_src[lane * OC + o];
                d += v[b] * att_dst[lane * OC + o];
            }
        }
    }
    as_[(size_t)node * NH + lane] = s;
    ad_[(size_t)node * NH + lane] = d;
}

// ---------------- node-boundary flush for the fused streaming aggregate ----------------
// acc holds UNNORMALIZED weighted sums; divide by den here.
// LAYER==1: bf16 h1p[cur][slice] = BN1(ELU(acc/den + b1))
// LAYER==2: head-reduce in-wave, write per-slice partial (non-atomic) to h2part[cur][f][32]
template <int LAYER>
__device__ __forceinline__ void flush_node(float* acc, float den, int cur, int f, int lane,
                                           const float* __restrict__ bias,
                                           const float* __restrict__ bng,
                                           const float* __restrict__ bnb,
                                           const float* __restrict__ bnm,
                                           const float* __restrict__ bnv,
                                           void* __restrict__ outp) {
    float inv = 1.f / den;
    #pragma unroll
    for (int k = 0; k < 4; ++k) acc[k] *= inv;

    if constexpr (LAYER == 1) {
        int d0 = f * 256 + lane * 4;
        u32 r01, r23;
        {
            float v0 = acc[0] + bias[d0 + 0];
            float v1 = acc[1] + bias[d0 + 1];
            float v2 = acc[2] + bias[d0 + 2];
            float v3 = acc[3] + bias[d0 + 3];
            v0 = v0 > 0.f ? v0 : expm1f(v0);
            v1 = v1 > 0.f ? v1 : expm1f(v1);
            v2 = v2 > 0.f ? v2 : expm1f(v2);
            v3 = v3 > 0.f ? v3 : expm1f(v3);
            v0 = (v0 - bnm[d0 + 0]) * rsqrtf(bnv[d0 + 0] + EPS_BN) * bng[d0 + 0] + bnb[d0 + 0];
            v1 = (v1 - bnm[d0 + 1]) * rsqrtf(bnv[d0 + 1] + EPS_BN) * bng[d0 + 1] + bnb[d0 + 1];
            v2 = (v2 - bnm[d0 + 2]) * rsqrtf(bnv[d0 + 2] + EPS_BN) * bng[d0 + 2] + bnb[d0 + 2];
            v3 = (v3 - bnm[d0 + 3]) * rsqrtf(bnv[d0 + 3] + EPS_BN) * bng[d0 + 3] + bnb[d0 + 3];
            __hip_bfloat16 b0 = __float2bfloat16(v0), b1 = __float2bfloat16(v1);
            __hip_bfloat16 b2 = __float2bfloat16(v2), b3 = __float2bfloat16(v3);
            r01 = (u32)*(unsigned short*)&b0 | ((u32)*(unsigned short*)&b1 << 16);
            r23 = (u32)*(unsigned short*)&b2 | ((u32)*(unsigned short*)&b3 << 16);
        }
        uint2 pk; pk.x = r01; pk.y = r23;
        *(uint2*)((__hip_bfloat16*)outp + (size_t)cur * DD1 + d0) = pk;
    } else {
        // sum over the 8 heads held by this wave (lane groups stride 8)
        #pragma unroll
        for (int k = 0; k < 4; ++k) {
            acc[k] += __shfl_xor(acc[k], 8, 64);
            acc[k] += __shfl_xor(acc[k], 16, 64);
            acc[k] += __shfl_xor(acc[k], 32, 64);
        }
        if (lane < 8) {
            floatx4 pk;
            #pragma unroll
            for (int k = 0; k < 4; ++k) pk[k] = acc[k] * (1.f / NH);
            *(floatx4*)((float*)outp + ((size_t)cur * 7 + f) * OC + lane * 4) = pk;
        }
    }
    acc[0] = acc[1] = acc[2] = acc[3] = 0.f;
}

// ---------------- fused streaming aggregation with ONLINE SOFTMAX ----------------
// wave = (slice f in [0,7), node group of GRP nodes). Lane covers 4 fp8 features
// at byte offset f*256 + lane*4, head = f*8 + (lane>>3). Per edge: gather h row
// u32 + as[src][head]; online max/den rescale; flush (divide by den) at bounds.
template <int LAYER>
__global__ __launch_bounds__(256) void attn_aggregate(const int* __restrict__ rowptr,
                                                      const int* __restrict__ csr_src,
                                                      const float* __restrict__ as_,
                                                      const float* __restrict__ ad_,
                                                      const unsigned char* __restrict__ h8,
                                                      const float* __restrict__ bias,
                                                      const float* __restrict__ bng,
                                                      const float* __restrict__ bnb,
                                                      const float* __restrict__ bnm,
                                                      const float* __restrict__ bnv,
                                                      void* __restrict__ outp) {
    const int wv = threadIdx.x >> 6, lane = threadIdx.x & 63;
    const int w = blockIdx.x * 4 + wv;
    const int NWAVES = 7 * (NN / GRP);
    if (w >= NWAVES) return;
    const int f  = w % 7;             // feature slice (256 B of the 1792-B row)
    const int g  = w / 7;             // node group
    const int n0 = g * GRP;
    const int off  = f * 256 + lane * 4;
    const int head = f * 8 + (lane >> 3);

    const int e0 = rowptr[n0], e1 = rowptr[n0 + GRP];
    int cur = n0;
    int bound = rowptr[n0 + 1];
    float adv = ad_[(size_t)cur * NH + head];

    float acc[4] = {0.f, 0.f, 0.f, 0.f};
    float m = -1e30f, den = 0.f;

    for (int e = e0; e < e1; e += EB) {
        u32   hv[EB];
        float sv[EB];
        // unconditional clamp-padded loads: EB independent chains in flight
        #pragma unroll
        for (int i = 0; i < EB; ++i) {
            int idx = (e + i < e1) ? e + i : e1 - 1;
            int s = csr_src[idx];
            hv[i] = *(const u32*)(h8 + (size_t)s * DD1 + off);
            sv[i] = as_[(size_t)s * NH + head];
        }
        #pragma unroll
        for (int i = 0; i < EB; ++i) {
            if (e + i >= e1) break;                 // tail padding: skip
            if (e + i >= bound) {                   // crossed into next node
                flush_node<LAYER>(acc, den, cur, f, lane, bias, bng, bnb, bnm, bnv, outp);
                ++cur;
                bound = rowptr[cur + 1];
                adv = ad_[(size_t)cur * NH + head];
                m = -1e30f; den = 0.f;
            }
            float lr = sv[i] + adv;
            lr = lr > 0.f ? lr : 0.2f * lr;         // leaky_relu
            float wgt;
            if (lr > m) {                           // new max: rescale history
                float scale = __expf(m - lr);
                den = den * scale + 1.f;
                #pragma unroll
                for (int k = 0; k < 4; ++k) acc[k] *= scale;
                m = lr;
                wgt = 1.f;
            } else {
                wgt = __expf(lr - m);
                den += wgt;
            }
            fma_fp8x4(hv[i], wgt, acc);
        }
    }
    flush_node<LAYER>(acc, den, cur, f, lane, bias, bng, bnb, bnm, bnv, outp);
}

// ---------------- mean pool: sum 7 slice-partials, atomic into graph sums ----------------
__global__ __launch_bounds__(256) void pool_kernel(const float* __restrict__ h2part,
                                                   const int* __restrict__ batch,
                                                   float* __restrict__ sums,
                                                   float* __restrict__ cnt) {
    int gid = blockIdx.x * 256 + threadIdx.x;
    if (gid >= NN * OC) return;
    int node = gid >> 5, ch = gid & 31;
    float v = 0.f;
    #pragma unroll
    for (int f = 0; f < 7; ++f) v += h2part[((size_t)node * 7 + f) * OC + ch];
    int g = batch[node];
    atomicAdd(&sums[g * OC + ch], v);
    if (ch == 0) atomicAdd(&cnt[g], 1.0f);
}

// final: pooled = sums/cnt; v = BN2(pooled + b2); out = v @ lin_w + lin_b
__global__ __launch_bounds__(128) void final_kernel(const float* __restrict__ sums,
                                                    const float* __restrict__ cnt,
                                                    const float* __restrict__ b2,
                                                    const float* __restrict__ bn2g,
                                                    const float* __restrict__ bn2b,
                                                    const float* __restrict__ bn2m,
                                                    const float* __restrict__ bn2v,
                                                    const float* __restrict__ lin_w,
                                                    const float* __restrict__ lin_b,
                                                    float* __restrict__ out) {
    int t = threadIdx.x;
    if (t >= NG * 2) return;
    int g = t >> 1, c = t & 1;
    float invc = 1.f / fmaxf(cnt[g], 1.f);
    float acc = lin_b[c];
    #pragma unroll
    for (int o = 0; o < OC; ++o) {
        float pooled = sums[g * OC + o] * invc + b2[o];
        float v = (pooled - bn2m[o]) * rsqrtf(bn2v[o] + EPS_BN) * bn2g[o] + bn2b[o];
        acc += v * lin_w[o * 2 + c];
    }
    out[t] = acc;
}

// ---------------- host-side launch ----------------
extern "C" void kernel_launch(void* const* d_in, const int* in_sizes, int n_in,
                              void* d_out, int out_size, void* d_ws, size_t ws_size,
                              hipStream_t stream) {
    const float* x    = (const float*)d_in[0];
    const int*   ei   = (const int*)d_in[1];
    const int*   bat  = (const int*)d_in[2];
    const float* W1   = (const float*)d_in[3];
    const float* at_s1 = (const float*)d_in[4];
    const float* at_d1 = (const float*)d_in[5];
    const float* b1   = (const float*)d_in[6];
    const float* bn1g = (const float*)d_in[7];
    const float* bn1b = (const float*)d_in[8];
    const float* bn1m = (const float*)d_in[9];
    const float* bn1v = (const float*)d_in[10];
    const float* W2   = (const float*)d_in[11];
    const float* at_s2 = (const float*)d_in[12];
    const float* at_d2 = (const float*)d_in[13];
    const float* b2   = (const float*)d_in[14];
    const float* bn2g = (const float*)d_in[15];
    const float* bn2b = (const float*)d_in[16];
    const float* bn2m = (const float*)d_in[17];
    const float* bn2v = (const float*)d_in[18];
    const float* linw = (const float*)d_in[19];
    const float* linb = (const float*)d_in[20];
    float* out = (float*)d_out;

    char* wsp = (char*)d_ws;
    auto alloc = [&](size_t bytes) -> void* {
        void* p = (void*)wsp;
        wsp += (bytes + 255) & ~(size_t)255;
        return p;
    };
    unsigned char*  h8  = (unsigned char*)alloc((size_t)NN * DD1);      // fp8 gemm output
    __hip_bfloat16* h1p = (__hip_bfloat16*)alloc((size_t)NN * DD1 * 2); // agg1 out (gemm2 A)
    __hip_bfloat16* xb  = (__hip_bfloat16*)alloc((size_t)NN * NF * 2);
    __hip_bfloat16* w1t = (__hip_bfloat16*)alloc((size_t)DD1 * NF * 2);
    __hip_bfloat16* w2t = (__hip_bfloat16*)alloc((size_t)DD1 * DD1 * 2);
    float* asb   = (float*)alloc((size_t)NN * NH * 4);
    float* adb   = (float*)alloc((size_t)NN * NH * 4);
    int*   deg   = (int*)alloc((size_t)NN * 4);
    int*   rowp  = (int*)alloc((size_t)(NN + 1) * 4);
    int*   curs  = (int*)alloc((size_t)NN * 4);
    int*   csr   = (int*)alloc((size_t)ETOT * 4);
    float* h2part = (float*)alloc((size_t)NN * 7 * OC * 4);
    float* sums  = (float*)alloc((size_t)(NG * OC + NG) * 4);
    float* cnt   = sums + NG * OC;

    hipMemsetAsync(deg, 0, (size_t)NN * 4, stream);
    hipMemsetAsync(sums, 0, (size_t)(NG * OC + NG) * 4, stream);

    cast_bf16_kernel<<<(NN * NF + 255) / 256, 256, 0, stream>>>(x, xb, NN * NF);
    transpose_cast_kernel<<<dim3(DD1 / 32, NF / 32), 256, 0, stream>>>(W1, w1t, NF, DD1);
    transpose_cast_kernel<<<dim3(DD1 / 32, DD1 / 32), 256, 0, stream>>>(W2, w2t, DD1, DD1);
    hist_kernel<<<(ETOT + 255) / 256, 256, 0, stream>>>(ei, deg);
    scan_kernel<<<1, 1024, 0, stream>>>(deg, rowp, curs);
    scatter_kernel<<<(ETOT + 255) / 256, 256, 0, stream>>>(ei, curs, csr);

    const int AGG_BLOCKS = (7 * (NN / GRP) + 3) / 4;
    const int NBY192 = (NN + 191) / 192;                   // 105
    const int GEMM_BLOCKS = NBY192 * (DD1 / 256);          // 735

    // layer 1
    gemm_192<<<GEMM_BLOCKS, 512, 0, stream>>>(xb, w1t, h8, NN, DD1, NF);
    attn_score<<<NN / 4, 256, 0, stream>>>(h8, at_s1, at_d1, asb, adb);
    attn_aggregate<1><<<AGG_BLOCKS, 256, 0, stream>>>(rowp, csr, asb, adb, h8, b1, bn1g, bn1b, bn1m, bn1v, (void*)h1p);

    // layer 2
    gemm_192<<<GEMM_BLOCKS, 512, 0, stream>>>(h1p, w2t, h8, NN, DD1, DD1);
    attn_score<<<NN / 4, 256, 0, stream>>>(h8, at_s2, at_d2, asb, adb);
    attn_aggregate<2><<<AGG_BLOCKS, 256, 0, stream>>>(rowp, csr, asb, adb, h8, b2, bn2g, bn2b, bn2m, bn2v, (void*)h2part);

    pool_kernel<<<(NN * OC) / 256, 256, 0, stream>>>(h2part, bat, sums, cnt);
    final_kernel<<<1, 128, 0, stream>>>(sums, cnt, b2, bn2g, bn2b, bn2m, bn2v, linw, linb, out);
}

// Round 5
// 575.290 us; speedup vs baseline: 1.3196x; 1.2461x over previous
//
#include <hip/hip_runtime.h>
#include <hip/hip_bf16.h>
#include <hip/hip_fp8.h>
#include <cstdint>
#include <cstddef>

// Problem constants
#define NN     20000     // nodes
#define NF     128       // in features
#define NH     56        // heads
#define OC     32        // out channels per head
#define DD1    1792      // NH*OC
#define NE     100000    // edges (before self loops)
#define ETOT   120000    // edges + self loops
#define NG     50        // graphs
#define EPS_BN 1e-5f
#define GRP    16        // nodes per wave in aggregate
#define EB     16        // edge batch (aggregate loads in flight)

typedef __bf16 bf16x8 __attribute__((ext_vector_type(8)));
typedef float  floatx4 __attribute__((ext_vector_type(4)));
typedef float  floatx2 __attribute__((ext_vector_type(2)));
typedef unsigned int u32;
typedef __attribute__((address_space(1))) u32 gu32;
typedef __attribute__((address_space(3))) u32 lu32;

__device__ __forceinline__ void async_copy16(void* lds, const void* g) {
    __builtin_amdgcn_global_load_lds((gu32*)const_cast<void*>(g), (lu32*)lds, 16, 0, 0);
}

// decode 4 fp8 (e4m3, packed in u32) to 4 floats (HW cvt when available)
__device__ __forceinline__ void dec_fp8x4(u32 u, float* v) {
#if __has_builtin(__builtin_amdgcn_cvt_pk_f32_fp8)
    floatx2 lo = __builtin_amdgcn_cvt_pk_f32_fp8(u, false);
    floatx2 hi = __builtin_amdgcn_cvt_pk_f32_fp8(u, true);
    v[0] = lo[0]; v[1] = lo[1]; v[2] = hi[0]; v[3] = hi[1];
#else
    #pragma unroll
    for (int b = 0; b < 4; ++b) {
        __hip_fp8_e4m3 t;
        t.__x = (u >> (8 * b)) & 0xff;
        v[b] = (float)t;
    }
#endif
}

__device__ __forceinline__ void fma_fp8x4(u32 u, float a, float* acc) {
    float v[4];
    dec_fp8x4(u, v);
    #pragma unroll
    for (int b = 0; b < 4; ++b) acc[b] += a * v[b];
}

// ---------------- elementwise cast fp32 -> bf16 ----------------
__global__ __launch_bounds__(256) void cast_bf16_kernel(const float* __restrict__ in,
                                                        __hip_bfloat16* __restrict__ out, int n) {
    int i = blockIdx.x * 256 + threadIdx.x;
    if (i < n) out[i] = __float2bfloat16(in[i]);
}

// ---------------- tiled transpose + cast: in[R][C] f32 -> out[C][R] bf16 ----------------
__global__ __launch_bounds__(256) void transpose_cast_kernel(const float* __restrict__ in,
                                                             __hip_bfloat16* __restrict__ out,
                                                             int R, int C) {
    __shared__ float tile[32][33];
    int c0 = blockIdx.x * 32, r0 = blockIdx.y * 32;
    int tx = threadIdx.x & 31, ty = threadIdx.x >> 5;   // ty in 0..7
    #pragma unroll
    for (int i = 0; i < 32; i += 8) {
        int r = r0 + ty + i, c = c0 + tx;
        if (r < R && c < C) tile[ty + i][tx] = in[(size_t)r * C + c];
    }
    __syncthreads();
    #pragma unroll
    for (int i = 0; i < 32; i += 8) {
        int c = c0 + ty + i, r = r0 + tx;
        if (c < C && r < R) out[(size_t)c * R + r] = __float2bfloat16(tile[tx][ty + i]);
    }
}

// ---------------- CSR build: histogram / scan / scatter ----------------
__global__ __launch_bounds__(256) void hist_kernel(const int* __restrict__ ei, int* __restrict__ deg) {
    int i = blockIdx.x * 256 + threadIdx.x;
    if (i >= ETOT) return;
    int dst = (i < NE) ? ei[NE + i] : (i - NE);
    atomicAdd(&deg[dst], 1);
}

__global__ __launch_bounds__(1024) void scan_kernel(const int* __restrict__ deg,
                                                    int* __restrict__ rowptr,
                                                    int* __restrict__ cursor) {
    __shared__ int buf[1024];
    int t = threadIdx.x;
    const int CH = (NN + 1023) >> 10;   // 20
    int base = t * CH;
    int s = 0;
    for (int j = 0; j < CH; ++j) { int idx = base + j; if (idx < NN) s += deg[idx]; }
    buf[t] = s;
    __syncthreads();
    for (int off = 1; off < 1024; off <<= 1) {
        int v = (t >= off) ? buf[t - off] : 0;
        __syncthreads();
        buf[t] += v;
        __syncthreads();
    }
    int run = buf[t] - s;   // exclusive
    for (int j = 0; j < CH; ++j) {
        int idx = base + j;
        if (idx < NN) { rowptr[idx] = run; cursor[idx] = run; run += deg[idx]; }
    }
    if (t == 1023) rowptr[NN] = buf[1023];
}

__global__ __launch_bounds__(256) void scatter_kernel(const int* __restrict__ ei,
                                                      int* __restrict__ cursor,
                                                      int* __restrict__ csr_src) {
    int i = blockIdx.x * 256 + threadIdx.x;
    if (i >= ETOT) return;
    int s, d;
    if (i < NE) { s = ei[i]; d = ei[NE + i]; } else { s = i - NE; d = i - NE; }
    int pos = atomicAdd(&cursor[d], 1);
    csr_src[pos] = s;
}

// ---------------- bf16 MFMA GEMM, 192x256 tile, 3-phase-per-K-tile schedule ----------------
// 8 waves (2M x 4N), per-wave C 96x64, BK=64, 2 LDS buffers (A[192][64]+B[256][64] = 56KB each).
// Grid 105x7 = 735 blocks = 2.87/CU -> 3 rounds at 96% CU utilization (vs 553 -> 72%).
// Per K-tile (BK=64), 3 phases, each {ds_reads || stage -> barrier -> MFMA -> barrier}:
//   PhA: read aF g0 (6 b128) + bA (4)          | no stage            | 12 MFMA Q(0,0)
//   PhB: read bB (4)                            | stage B(t+2) 4 ld  | 12 MFMA Q(0,1)
//   PhC: read aF g1 (6)                         | stage A(t+2) 3 ld  | 24 MFMA Q(1,1)+Q(1,0)
// Counted vmcnt(7) ONCE per tile at PhC (7 loads/tile/wave; 14 in flight at the wait ->
// retires exactly tile t+1 before PhA(t+1) reads it; never drained: T4). Stage placement:
// every staged region's last ds_reads are issued in the same or an earlier phase (same
// safety argument as the round-2 passing kernel / m201). Tail: parity-preserving clamp
// (tp -= 2) restages identical data -> benign, uniform vmcnt accounting.
// LDS swizzle: chunk c of 128B row r stored at c ^ (r&7); reads land 2 lanes/bank
// (free); measured 0 conflicts in prior rounds.
__global__ __launch_bounds__(512, 2) void gemm_192(const __hip_bfloat16* __restrict__ A,
                                                   const __hip_bfloat16* __restrict__ Bt,
                                                   unsigned char* __restrict__ C8,
                                                   int M, int N, int K) {
    __shared__ __align__(16) unsigned short lds[2][28672];  // per buf: A[192][64] | B[256][64]
    const int tid  = threadIdx.x;
    const int lane = tid & 63, wave = tid >> 6;
    const int wm = wave >> 2, wn = wave & 3;     // 2 x 4 wave grid; per-wave C: 96 x 64

    const int nbx = N >> 8;                      // 7
    const int nby = (M + 191) / 192;             // 105
    const int nwg = nbx * nby;                   // 735
    // bijective XCD swizzle (m204); bx fastest => A-panel L2 locality within XCD
    const int q = nwg >> 3, r = nwg & 7;
    const int xcd = blockIdx.x & 7, bidx = blockIdx.x >> 3;
    const int wg = (xcd < r ? xcd * (q + 1) : r * (q + 1) + (xcd - r) * q) + bidx;
    const int by = wg / nbx, bx = wg - by * nbx;
    const int m0 = by * 192, n0 = bx << 8;

    const int NT = K >> 6;                       // K-tiles of 64: 28 (L2) / 2 (L1)

    const int qq = lane >> 4, rr = lane & 15;

    // stage A of K-tile kt into buf b: 192 rows x 8 chunks = 1536 slots = 3 loads/thread
    auto stageA = [&](int kt, int b) {
        #pragma unroll
        for (int i = 0; i < 3; ++i) {
            int slot = i * 512 + tid;
            int row = slot >> 3, pch = slot & 7;
            int lc = pch ^ (row & 7);            // pre-swizzled global source (rule #21)
            int gr = m0 + row; if (gr > M - 1) gr = M - 1;
            async_copy16(&lds[b][slot * 8], A + (size_t)gr * K + (kt << 6) + lc * 8);
        }
    };
    // stage B of K-tile kt into buf b: 256 rows x 8 chunks = 2048 slots = 4 loads/thread
    auto stageB = [&](int kt, int b) {
        #pragma unroll
        for (int i = 0; i < 4; ++i) {
            int slot = i * 512 + tid;
            int row = slot >> 3, pch = slot & 7;
            int lc = pch ^ (row & 7);
            async_copy16(&lds[b][12288 + slot * 8], Bt + (size_t)(n0 + row) * K + (kt << 6) + lc * 8);
        }
    };

    floatx4 zero = {0.f, 0.f, 0.f, 0.f};
    floatx4 acc[6][4];
    #pragma unroll
    for (int i = 0; i < 6; ++i)
        #pragma unroll
        for (int jj = 0; jj < 4; ++jj) acc[i][jj] = zero;

    bf16x8 aF[3][2], bA[2][2], bB[2][2];

    auto loadA = [&](int b, int mg) {            // m-group mg: 3 frags, rows wm*96 + mg*48 + mf*16
        #pragma unroll
        for (int mf = 0; mf < 3; ++mf)
            #pragma unroll
            for (int s = 0; s < 2; ++s) {
                int row = wm * 96 + mg * 48 + mf * 16 + rr;
                int pch = (s * 4 + qq) ^ (row & 7);
                aF[mf][s] = *(const bf16x8*)&lds[b][row * 64 + pch * 8];
            }
    };
    auto loadB = [&](int b, bf16x8 (&bF)[2][2], int ng) {
        #pragma unroll
        for (int nf = 0; nf < 2; ++nf)
            #pragma unroll
            for (int s = 0; s < 2; ++s) {
                int row = wn * 64 + (ng * 2 + nf) * 16 + rr;
                int pch = (s * 4 + qq) ^ (row & 7);
                bF[nf][s] = *(const bf16x8*)&lds[b][12288 + row * 64 + pch * 8];
            }
    };
    auto mfmaQ = [&](int mg, int ng, bf16x8 (&bF)[2][2]) {   // 12 MFMA quadrant
        #pragma unroll
        for (int mf = 0; mf < 3; ++mf)
            #pragma unroll
            for (int nf = 0; nf < 2; ++nf)
                #pragma unroll
                for (int s = 0; s < 2; ++s)
                    acc[mg * 3 + mf][ng * 2 + nf] = __builtin_amdgcn_mfma_f32_16x16x32_bf16(
                        aF[mf][s], bF[nf][s], acc[mg * 3 + mf][ng * 2 + nf], 0, 0, 0);
    };

#define SB0 __builtin_amdgcn_sched_barrier(0)
#define GBAR do { SB0; __builtin_amdgcn_s_barrier(); SB0; } while (0)

    // prologue: tiles 0,1 staged (B then A per tile, 7 loads each = 14 in flight)
    stageB(0, 0); stageA(0, 0);
    stageB(1, 1); stageA(1, 1);
    SB0;
    asm volatile("s_waitcnt vmcnt(7)" ::: "memory");         // tile0 landed; tile1 in flight
    GBAR;

    for (int t = 0; t < NT; ++t) {
        const int p = t & 1;
        int tp = t + 2; while (tp >= NT) tp -= 2;            // parity-preserving tail clamp

        // PhA: reads aF g0 + bA (10 ds_reads); no stage
        loadA(p, 0); loadB(p, bA, 0);
        GBAR;
        __builtin_amdgcn_s_setprio(1);
        mfmaQ(0, 0, bA);
        __builtin_amdgcn_s_setprio(0);
        GBAR;

        // PhB: reads bB (4); stage B(t+2) -> buf p (bA-set reads completed PhA; bB issued here)
        loadB(p, bB, 1);
        stageB(tp, p);
        GBAR;
        __builtin_amdgcn_s_setprio(1);
        mfmaQ(0, 1, bB);
        __builtin_amdgcn_s_setprio(0);
        GBAR;

        // PhC: reads aF g1 (6); stage A(t+2) -> buf p; vmcnt(7): tile t+1 fully landed
        loadA(p, 1);
        stageA(tp, p);
        SB0;
        asm volatile("s_waitcnt vmcnt(7)" ::: "memory");
        GBAR;
        __builtin_amdgcn_s_setprio(1);
        mfmaQ(1, 1, bB);
        mfmaQ(1, 0, bA);
        __builtin_amdgcn_s_setprio(0);
        GBAR;
    }
#undef GBAR
#undef SB0

    // epilogue: fp8 quantize + store
    #pragma unroll
    for (int mt = 0; mt < 6; ++mt) {
        #pragma unroll
        for (int r4 = 0; r4 < 4; ++r4) {
            int rowc = m0 + wm * 96 + mt * 16 + (lane >> 4) * 4 + r4;
            if (rowc < M) {
                float v0 = acc[mt][0][r4], v1 = acc[mt][1][r4];
                float v2 = acc[mt][2][r4], v3 = acc[mt][3][r4];
                unsigned char q8[4];
#if __has_builtin(__builtin_amdgcn_cvt_pk_fp8_f32)
                u32 p01 = (u32)__builtin_amdgcn_cvt_pk_fp8_f32(v0, v1, 0, false);
                u32 p23 = (u32)__builtin_amdgcn_cvt_pk_fp8_f32(v2, v3, 0, false);
                q8[0] = p01 & 0xff; q8[1] = (p01 >> 8) & 0xff;
                q8[2] = p23 & 0xff; q8[3] = (p23 >> 8) & 0xff;
#else
                { __hip_fp8_e4m3 t0(v0), t1(v1), t2(v2), t3(v3);
                  q8[0] = t0.__x; q8[1] = t1.__x; q8[2] = t2.__x; q8[3] = t3.__x; }
#endif
                #pragma unroll
                for (int nt = 0; nt < 4; ++nt) {
                    int col = n0 + wn * 64 + nt * 16 + (lane & 15);
                    C8[(size_t)rowc * N + col] = q8[nt];
                }
            }
        }
    }
}

// ---------------- attention scores from fp8 h: as/ad[n,h] = sum_o h[n,h,o]*att[h,o] ----------------
__global__ __launch_bounds__(256) void attn_score(const unsigned char* __restrict__ h8,
                                                  const float* __restrict__ att_src,
                                                  const float* __restrict__ att_dst,
                                                  float* __restrict__ as_,
                                                  float* __restrict__ ad_) {
    int wave = threadIdx.x >> 6, lane = threadIdx.x & 63;
    int node = blockIdx.x * 4 + wave;
    if (node >= NN || lane >= NH) return;
    const uint2* hp = (const uint2*)(h8 + (size_t)node * DD1 + lane * OC);   // 32 B / head
    float s = 0.f, d = 0.f;
    #pragma unroll
    for (int jj = 0; jj < 4; ++jj) {
        uint2 u2 = hp[jj];
        u32 us[2] = {u2.x, u2.y};
        #pragma unroll
        for (int w = 0; w < 2; ++w) {
            float v[4];
            dec_fp8x4(us[w], v);
            #pragma unroll
            for (int b = 0; b < 4; ++b) {
                int o = jj * 8 + w * 4 + b;
                s += v[b] * att_src[lane * OC + o];
                d += v[b] * att_dst[lane * OC + o];
            }
        }
    }
    as_[(size_t)node * NH + lane] = s;
    ad_[(size_t)node * NH + lane] = d;
}

// ---------------- node-boundary flush for the fused streaming aggregate ----------------
// acc holds UNNORMALIZED weighted sums; divide by den here.
// LAYER==1: bf16 h1p[cur][slice] = BN1(ELU(acc/den + b1))
// LAYER==2: head-reduce in-wave, write per-slice partial (non-atomic) to h2part[cur][f][32]
template <int LAYER>
__device__ __forceinline__ void flush_node(float* acc, float den, int cur, int f, int lane,
                                           const float* __restrict__ bias,
                                           const float* __restrict__ bng,
                                           const float* __restrict__ bnb,
                                           const float* __restrict__ bnm,
                                           const float* __restrict__ bnv,
                                           void* __restrict__ outp) {
    float inv = 1.f / den;
    #pragma unroll
    for (int k = 0; k < 4; ++k) acc[k] *= inv;

    if constexpr (LAYER == 1) {
        int d0 = f * 256 + lane * 4;
        u32 r01, r23;
        {
            float v0 = acc[0] + bias[d0 + 0];
            float v1 = acc[1] + bias[d0 + 1];
            float v2 = acc[2] + bias[d0 + 2];
            float v3 = acc[3] + bias[d0 + 3];
            v0 = v0 > 0.f ? v0 : expm1f(v0);
            v1 = v1 > 0.f ? v1 : expm1f(v1);
            v2 = v2 > 0.f ? v2 : expm1f(v2);
            v3 = v3 > 0.f ? v3 : expm1f(v3);
            v0 = (v0 - bnm[d0 + 0]) * rsqrtf(bnv[d0 + 0] + EPS_BN) * bng[d0 + 0] + bnb[d0 + 0];
            v1 = (v1 - bnm[d0 + 1]) * rsqrtf(bnv[d0 + 1] + EPS_BN) * bng[d0 + 1] + bnb[d0 + 1];
            v2 = (v2 - bnm[d0 + 2]) * rsqrtf(bnv[d0 + 2] + EPS_BN) * bng[d0 + 2] + bnb[d0 + 2];
            v3 = (v3 - bnm[d0 + 3]) * rsqrtf(bnv[d0 + 3] + EPS_BN) * bng[d0 + 3] + bnb[d0 + 3];
            __hip_bfloat16 b0 = __float2bfloat16(v0), b1 = __float2bfloat16(v1);
            __hip_bfloat16 b2 = __float2bfloat16(v2), b3 = __float2bfloat16(v3);
            r01 = (u32)*(unsigned short*)&b0 | ((u32)*(unsigned short*)&b1 << 16);
            r23 = (u32)*(unsigned short*)&b2 | ((u32)*(unsigned short*)&b3 << 16);
        }
        uint2 pk; pk.x = r01; pk.y = r23;
        *(uint2*)((__hip_bfloat16*)outp + (size_t)cur * DD1 + d0) = pk;
    } else {
        // sum over the 8 heads held by this wave (lane groups stride 8)
        #pragma unroll
        for (int k = 0; k < 4; ++k) {
            acc[k] += __shfl_xor(acc[k], 8, 64);
            acc[k] += __shfl_xor(acc[k], 16, 64);
            acc[k] += __shfl_xor(acc[k], 32, 64);
        }
        if (lane < 8) {
            floatx4 pk;
            #pragma unroll
            for (int k = 0; k < 4; ++k) pk[k] = acc[k] * (1.f / NH);
            *(floatx4*)((float*)outp + ((size_t)cur * 7 + f) * OC + lane * 4) = pk;
        }
    }
    acc[0] = acc[1] = acc[2] = acc[3] = 0.f;
}

// ---------------- fused streaming aggregation with ONLINE SOFTMAX ----------------
// wave = (slice f in [0,7), node group of GRP nodes). Lane covers 4 fp8 features
// at byte offset f*256 + lane*4, head = f*8 + (lane>>3). Per edge: gather h row
// u32 + as[src][head]; online max/den rescale; flush (divide by den) at bounds.
template <int LAYER>
__global__ __launch_bounds__(256) void attn_aggregate(const int* __restrict__ rowptr,
                                                      const int* __restrict__ csr_src,
                                                      const float* __restrict__ as_,
                                                      const float* __restrict__ ad_,
                                                      const unsigned char* __restrict__ h8,
                                                      const float* __restrict__ bias,
                                                      const float* __restrict__ bng,
                                                      const float* __restrict__ bnb,
                                                      const float* __restrict__ bnm,
                                                      const float* __restrict__ bnv,
                                                      void* __restrict__ outp) {
    const int wv = threadIdx.x >> 6, lane = threadIdx.x & 63;
    const int w = blockIdx.x * 4 + wv;
    const int NWAVES = 7 * (NN / GRP);
    if (w >= NWAVES) return;
    const int f  = w % 7;             // feature slice (256 B of the 1792-B row)
    const int g  = w / 7;             // node group
    const int n0 = g * GRP;
    const int off  = f * 256 + lane * 4;
    const int head = f * 8 + (lane >> 3);

    const int e0 = rowptr[n0], e1 = rowptr[n0 + GRP];
    int cur = n0;
    int bound = rowptr[n0 + 1];
    float adv = ad_[(size_t)cur * NH + head];

    float acc[4] = {0.f, 0.f, 0.f, 0.f};
    float m = -1e30f, den = 0.f;

    for (int e = e0; e < e1; e += EB) {
        u32   hv[EB];
        float sv[EB];
        // unconditional clamp-padded loads: EB independent chains in flight
        #pragma unroll
        for (int i = 0; i < EB; ++i) {
            int idx = (e + i < e1) ? e + i : e1 - 1;
            int s = csr_src[idx];
            hv[i] = *(const u32*)(h8 + (size_t)s * DD1 + off);
            sv[i] = as_[(size_t)s * NH + head];
        }
        #pragma unroll
        for (int i = 0; i < EB; ++i) {
            if (e + i >= e1) break;                 // tail padding: skip
            if (e + i >= bound) {                   // crossed into next node
                flush_node<LAYER>(acc, den, cur, f, lane, bias, bng, bnb, bnm, bnv, outp);
                ++cur;
                bound = rowptr[cur + 1];
                adv = ad_[(size_t)cur * NH + head];
                m = -1e30f; den = 0.f;
            }
            float lr = sv[i] + adv;
            lr = lr > 0.f ? lr : 0.2f * lr;         // leaky_relu
            float wgt;
            if (lr > m) {                           // new max: rescale history
                float scale = __expf(m - lr);
                den = den * scale + 1.f;
                #pragma unroll
                for (int k = 0; k < 4; ++k) acc[k] *= scale;
                m = lr;
                wgt = 1.f;
            } else {
                wgt = __expf(lr - m);
                den += wgt;
            }
            fma_fp8x4(hv[i], wgt, acc);
        }
    }
    flush_node<LAYER>(acc, den, cur, f, lane, bias, bng, bnb, bnm, bnv, outp);
}

// ---------------- mean pool: sorted-batch segmented reduction, minimal atomics ----------------
// batch is SORTED -> graph g occupies contiguous [s,e). Grid = NG*8 blocks: block
// (g, chunk c) binary-searches its bounds (uniform, L2-cached), register-accumulates
// its node subrange (per-node 7x32 f32 = 896 B contiguous, fully coalesced), reduces
// the 8 node-lanes (shfl_xor 32 + LDS), and issues exactly 32 atomicAdd per block
// (12.8K total @ 8-way contention, vs 660K @ 400-way before: Guideline 12).
__global__ __launch_bounds__(256) void pool_kernel(const float* __restrict__ h2part,
                                                   const int* __restrict__ batch,
                                                   float* __restrict__ sums,
                                                   float* __restrict__ cnt) {
    __shared__ float red[4][OC];
    const int g = blockIdx.x >> 3, c = blockIdx.x & 7;
    const int t = threadIdx.x;
    const int ch = t & 31, nl = t >> 5;          // nl in 0..7
    // binary search graph bounds in sorted batch (uniform across threads)
    int lo = 0, hi = NN;
    while (lo < hi) { int mid = (lo + hi) >> 1; if (batch[mid] < g) lo = mid + 1; else hi = mid; }
    const int s = lo;
    hi = NN;
    while (lo < hi) { int mid = (lo + hi) >> 1; if (batch[mid] <= g) lo = mid + 1; else hi = mid; }
    const int e = lo;
    const int len = e - s;
    const int n0 = s + (len * c) / 8;
    const int n1 = s + (len * (c + 1)) / 8;
    float acc = 0.f;
    for (int n = n0 + nl; n < n1; n += 8) {
        const float* p = h2part + (size_t)n * 7 * OC + ch;
        float a = 0.f;
        #pragma unroll
        for (int f = 0; f < 7; ++f) a += p[f * OC];
        acc += a;
    }
    acc += __shfl_xor(acc, 32, 64);              // combine the wave's 2 node-lanes
    if ((t & 32) == 0) red[t >> 6][ch] = acc;    // one writer per (wave, ch)
    __syncthreads();
    if (t < OC) {
        float total = red[0][t] + red[1][t] + red[2][t] + red[3][t];
        atomicAdd(&sums[g * OC + t], total);
    }
    if (t == 0 && c == 0) cnt[g] = (float)len;   // single writer, no atomic
}

// final: pooled = sums/cnt; v = BN2(pooled + b2); out = v @ lin_w + lin_b
__global__ __launch_bounds__(128) void final_kernel(const float* __restrict__ sums,
                                                    const float* __restrict__ cnt,
                                                    const float* __restrict__ b2,
                                                    const float* __restrict__ bn2g,
                                                    const float* __restrict__ bn2b,
                                                    const float* __restrict__ bn2m,
                                                    const float* __restrict__ bn2v,
                                                    const float* __restrict__ lin_w,
                                                    const float* __restrict__ lin_b,
                                                    float* __restrict__ out) {
    int t = threadIdx.x;
    if (t >= NG * 2) return;
    int g = t >> 1, c = t & 1;
    float invc = 1.f / fmaxf(cnt[g], 1.f);
    float acc = lin_b[c];
    #pragma unroll
    for (int o = 0; o < OC; ++o) {
        float pooled = sums[g * OC + o] * invc + b2[o];
        float v = (pooled - bn2m[o]) * rsqrtf(bn2v[o] + EPS_BN) * bn2g[o] + bn2b[o];
        acc += v * lin_w[o * 2 + c];
    }
    out[t] = acc;
}

// ---------------- host-side launch ----------------
extern "C" void kernel_launch(void* const* d_in, const int* in_sizes, int n_in,
                              void* d_out, int out_size, void* d_ws, size_t ws_size,
                              hipStream_t stream) {
    const float* x    = (const float*)d_in[0];
    const int*   ei   = (const int*)d_in[1];
    const int*   bat  = (const int*)d_in[2];
    const float* W1   = (const float*)d_in[3];
    const float* at_s1 = (const float*)d_in[4];
    const float* at_d1 = (const float*)d_in[5];
    const float* b1   = (const float*)d_in[6];
    const float* bn1g = (const float*)d_in[7];
    const float* bn1b = (const float*)d_in[8];
    const float* bn1m = (const float*)d_in[9];
    const float* bn1v = (const float*)d_in[10];
    const float* W2   = (const float*)d_in[11];
    const float* at_s2 = (const float*)d_in[12];
    const float* at_d2 = (const float*)d_in[13];
    const float* b2   = (const float*)d_in[14];
    const float* bn2g = (const float*)d_in[15];
    const float* bn2b = (const float*)d_in[16];
    const float* bn2m = (const float*)d_in[17];
    const float* bn2v = (const float*)d_in[18];
    const float* linw = (const float*)d_in[19];
    const float* linb = (const float*)d_in[20];
    float* out = (float*)d_out;

    char* wsp = (char*)d_ws;
    auto alloc = [&](size_t bytes) -> void* {
        void* p = (void*)wsp;
        wsp += (bytes + 255) & ~(size_t)255;
        return p;
    };
    unsigned char*  h8  = (unsigned char*)alloc((size_t)NN * DD1);      // fp8 gemm output
    __hip_bfloat16* h1p = (__hip_bfloat16*)alloc((size_t)NN * DD1 * 2); // agg1 out (gemm2 A)
    __hip_bfloat16* xb  = (__hip_bfloat16*)alloc((size_t)NN * NF * 2);
    __hip_bfloat16* w1t = (__hip_bfloat16*)alloc((size_t)DD1 * NF * 2);
    __hip_bfloat16* w2t = (__hip_bfloat16*)alloc((size_t)DD1 * DD1 * 2);
    float* asb   = (float*)alloc((size_t)NN * NH * 4);
    float* adb   = (float*)alloc((size_t)NN * NH * 4);
    int*   deg   = (int*)alloc((size_t)NN * 4);
    int*   rowp  = (int*)alloc((size_t)(NN + 1) * 4);
    int*   curs  = (int*)alloc((size_t)NN * 4);
    int*   csr   = (int*)alloc((size_t)ETOT * 4);
    float* h2part = (float*)alloc((size_t)NN * 7 * OC * 4);
    float* sums  = (float*)alloc((size_t)(NG * OC + NG) * 4);
    float* cnt   = sums + NG * OC;

    hipMemsetAsync(deg, 0, (size_t)NN * 4, stream);
    hipMemsetAsync(sums, 0, (size_t)(NG * OC + NG) * 4, stream);

    cast_bf16_kernel<<<(NN * NF + 255) / 256, 256, 0, stream>>>(x, xb, NN * NF);
    transpose_cast_kernel<<<dim3(DD1 / 32, NF / 32), 256, 0, stream>>>(W1, w1t, NF, DD1);
    transpose_cast_kernel<<<dim3(DD1 / 32, DD1 / 32), 256, 0, stream>>>(W2, w2t, DD1, DD1);
    hist_kernel<<<(ETOT + 255) / 256, 256, 0, stream>>>(ei, deg);
    scan_kernel<<<1, 1024, 0, stream>>>(deg, rowp, curs);
    scatter_kernel<<<(ETOT + 255) / 256, 256, 0, stream>>>(ei, curs, csr);

    const int AGG_BLOCKS = (7 * (NN / GRP) + 3) / 4;
    const int NBY192 = (NN + 191) / 192;                   // 105
    const int GEMM_BLOCKS = NBY192 * (DD1 / 256);          // 735

    // layer 1
    gemm_192<<<GEMM_BLOCKS, 512, 0, stream>>>(xb, w1t, h8, NN, DD1, NF);
    attn_score<<<NN / 4, 256, 0, stream>>>(h8, at_s1, at_d1, asb, adb);
    attn_aggregate<1><<<AGG_BLOCKS, 256, 0, stream>>>(rowp, csr, asb, adb, h8, b1, bn1g, bn1b, bn1m, bn1v, (void*)h1p);

    // layer 2
    gemm_192<<<GEMM_BLOCKS, 512, 0, stream>>>(h1p, w2t, h8, NN, DD1, DD1);
    attn_score<<<NN / 4, 256, 0, stream>>>(h8, at_s2, at_d2, asb, adb);
    attn_aggregate<2><<<AGG_BLOCKS, 256, 0, stream>>>(rowp, csr, asb, adb, h8, b2, bn2g, bn2b, bn2m, bn2v, (void*)h2part);

    pool_kernel<<<NG * 8, 256, 0, stream>>>(h2part, bat, sums, cnt);
    final_kernel<<<1, 128, 0, stream>>>(sums, cnt, b2, bn2g, bn2b, bn2m, bn2v, linw, linb, out);
}